// Round 8
// baseline (236.699 us; speedup 1.0000x reference)
//
#include <hip/hip_runtime.h>

// ---------------------------------------------------------------------------
// EntropyPrunedSelfAttention  (B=4, N=1024, C=768, H=12, hd=64)
// Round 19 (= R18 resubmit; R18 bench was an infra failure, no signal).
// ks_fused = R15/R4 exact structure (proven 48us) + k_mask merged into the
// last-finishing block (saves one launch + gap). No spin-waits anywhere ->
// cannot deadlock; kc_conv re-zeroes done/keepCnt/colSP for graph replay.
//
// Workspace (byte offsets):
//   xb      bf16[4096*768]      @ 0
//   qwb     bf16[2304*768]      @ 6291456
//   pwb     bf16[768*768]       @ 9830400
//   qb      bf16[48*1024*64]    @ 11010048   (pre-scaled by 0.125*log2e)
//   kb      bf16[48*1024*64]    @ 17301504
//   v       f32 [48*1024*64]    @ 23592960
//   ctxb    bf16[4096*768]      @ 36175872
//   lse     f32 [48*1024]       @ 42467328   (log2 of row-sum Z)
//   mask    f32 [1024]          @ 42663936
//   keep    int [1]             @ 42668032
//   done    u32 [1]             @ 42668036
//   colSP   f32 [2048]          @ 42668544   (colS[1024] ++ colP_log2[1024])
// total ~42.7 MB
// ---------------------------------------------------------------------------

typedef __bf16 bf16x8 __attribute__((ext_vector_type(8)));
typedef __bf16 bf16x4 __attribute__((ext_vector_type(4)));
typedef float  f32x4  __attribute__((ext_vector_type(4)));

#define MFMA16(a, b, c) __builtin_amdgcn_mfma_f32_16x16x32_bf16((a), (b), (c), 0, 0, 0)
#define QSCALE 0.18033688f   /* 0.125 * log2(e) */
#define LN2    0.69314718f

#if __has_builtin(__builtin_amdgcn_exp2f)
#define EXP2(x) __builtin_amdgcn_exp2f(x)
#else
#define EXP2(x) exp2f(x)
#endif

__device__ __forceinline__ void ld_glds16(const __bf16* g, __bf16* s) {
  __builtin_amdgcn_global_load_lds(
      (const __attribute__((address_space(1))) unsigned int*)g,
      (__attribute__((address_space(3))) unsigned int*)s, 16, 0, 0);
}

// --- 1. fp32 -> bf16 conversion + zero colSP/keepCnt/done ------------------
__global__ __launch_bounds__(256) void kc_conv(
    const float* __restrict__ x, const float* __restrict__ qw, const float* __restrict__ pw,
    __bf16* __restrict__ xb, __bf16* __restrict__ qwb, __bf16* __restrict__ pwb,
    float* __restrict__ colSP, int* __restrict__ keepCnt, unsigned int* __restrict__ done)
{
  const int i = blockIdx.x * 256 + threadIdx.x;
  const float4* src;
  __bf16* dst;
  int j;
  if (i < 786432)       { src = (const float4*)x;  dst = xb;  j = i; }
  else if (i < 1228800) { src = (const float4*)qw; dst = qwb; j = i - 786432; }
  else                  { src = (const float4*)pw; dst = pwb; j = i - 1228800; }
  const float4 f = src[j];
  bf16x4 o;
  o[0] = (__bf16)f.x; o[1] = (__bf16)f.y; o[2] = (__bf16)f.z; o[3] = (__bf16)f.w;
  *(bf16x4*)(dst + 4 * (size_t)j) = o;
  if (i < 2048) colSP[i] = 0.f;
  if (i == 0) { *keepCnt = 0; *done = 0u; }
}

// --- 2. QKV GEMM, m97-style. Q part written pre-scaled by QSCALE. ----------
__global__ __launch_bounds__(256) void kg_qkv(
    const __bf16* __restrict__ A, const __bf16* __restrict__ Bm,
    __bf16* __restrict__ qb, __bf16* __restrict__ kb, float* __restrict__ v)
{
  __shared__ __bf16 As[128 * 64];
  __shared__ __bf16 Bs[128 * 64];
  const int tid = threadIdx.x;
  const int w = tid >> 6, lane = tid & 63, quad = lane >> 4, l = lane & 15;
  const int wm = w >> 1, wn = w & 1;
  const int r0 = blockIdx.y * 128, c0 = blockIdx.x * 128;
  const int srow = lane >> 3, skk = (lane & 7) * 8;

  f32x4 acc[4][4] = {};

  for (int k0 = 0; k0 < 768; k0 += 64) {
    if (k0) __syncthreads();
#pragma unroll
    for (int s = 0; s < 4; ++s) {
      const int si = w * 4 + s;               // 0..15
      const int row = si * 8 + srow;
      ld_glds16(A + (size_t)(r0 + row) * 768 + k0 + skk, &As[si * 512]);
      ld_glds16(Bm + (size_t)(c0 + row) * 768 + k0 + skk, &Bs[si * 512]);
    }
    __syncthreads();
#pragma unroll
    for (int kk = 0; kk < 2; ++kk) {
      bf16x8 af[4], bf[4];
#pragma unroll
      for (int t = 0; t < 4; ++t) {
        af[t] = *(const bf16x8*)&As[(wm * 64 + t * 16 + l) * 64 + kk * 32 + quad * 8];
        bf[t] = *(const bf16x8*)&Bs[(wn * 64 + t * 16 + l) * 64 + kk * 32 + quad * 8];
      }
#pragma unroll
      for (int mt = 0; mt < 4; ++mt)
#pragma unroll
        for (int nt = 0; nt < 4; ++nt)
          acc[mt][nt] = MFMA16(af[mt], bf[nt], acc[mt][nt]);
    }
  }

  const int part = c0 / 768;
  const int cbase = c0 % 768;
#pragma unroll
  for (int mt = 0; mt < 4; ++mt) {
#pragma unroll
    for (int nt = 0; nt < 4; ++nt) {
      const int cc = cbase + wn * 64 + nt * 16 + l;  // 0..767
      const int h = cc >> 6, d = cc & 63;
#pragma unroll
      for (int i = 0; i < 4; ++i) {
        const int rg = r0 + wm * 64 + mt * 16 + quad * 4 + i;
        const int b_ = rg >> 10, n = rg & 1023;
        const size_t off = ((size_t)(b_ * 12 + h) * 1024 + n) * 64 + d;
        const float val = acc[mt][nt][i];
        if (part == 0)      qb[off] = (__bf16)(val * QSCALE);
        else if (part == 1) kb[off] = (__bf16)val;
        else                v[off]  = val;
      }
    }
  }
}

// --- 3. fused stats (R15 structure, proven 48us) + last-block mask tail ----
// grid (48, 16), 512 threads (8 waves). Block = (bh, 64 rows) x 1024 cols.
// Chunk = 128 K-rows; wave w owns cols s*128 + w*16 + l. Per wave per chunk:
// 2 global dwordx4 (depth-1 prefetch), 8 MFMA batched, then 16 exp2 batched.
__global__ __launch_bounds__(512) void ks_fused(
    const __bf16* __restrict__ qb, const __bf16* __restrict__ kb,
    float* __restrict__ lse, float* __restrict__ colSP,
    const int* __restrict__ cur_epoch, float* __restrict__ mask,
    int* __restrict__ keepCnt, unsigned int* __restrict__ done)
{
  __shared__ float sS[1024];
  __shared__ float sP[1024];
  __shared__ float zrow[64];
  __shared__ int lastBlk;
  const int tid = threadIdx.x;
  const int w = tid >> 6, lane = tid & 63, quad = lane >> 4, l = lane & 15;
  const int bh = blockIdx.x, r0 = blockIdx.y * 64;
  for (int i = tid; i < 1024; i += 512) { sS[i] = 0.f; sP[i] = 0.f; }
  if (tid < 64) zrow[tid] = 0.f;
  __syncthreads();  // init visible

  // Q fragments (pre-scaled): rows r0 + rt*16 + l, dims quad*8 (+0 / +32)
  const __bf16* qbase = qb + ((size_t)bh * 1024 + r0 + l) * 64;
  bf16x8 aq0[4], aq1[4];
#pragma unroll
  for (int rt = 0; rt < 4; ++rt) {
    aq0[rt] = *(const bf16x8*)(qbase + rt * 1024 + quad * 8);
    aq1[rt] = *(const bf16x8*)(qbase + rt * 1024 + 32 + quad * 8);
  }
  // K fragment base: row (w*16 + l), dim quad*8; chunk s adds s*128*64 elems.
  const __bf16* kfrag = kb + (size_t)bh * 65536 + (size_t)(w * 16 + l) * 64 + quad * 8;
  const f32x4 zero = {0.f, 0.f, 0.f, 0.f};

  bf16x8 kf0 = *(const bf16x8*)(kfrag);
  bf16x8 kf1 = *(const bf16x8*)(kfrag + 32);

  float z[16] = {};
  // ---- pass 1: row sums of exp2(score) ----
  for (int s = 0; s < 8; ++s) {
    const bf16x8 c0 = kf0, c1 = kf1;
    const int nxt = (s + 1) & 7;  // s==7 prefetches chunk 0 for pass 2
    kf0 = *(const bf16x8*)(kfrag + (size_t)nxt * 8192);
    kf1 = *(const bf16x8*)(kfrag + (size_t)nxt * 8192 + 32);
    f32x4 av[4];
#pragma unroll
    for (int rt = 0; rt < 4; ++rt) {
      av[rt] = MFMA16(aq0[rt], c0, zero);
      av[rt] = MFMA16(aq1[rt], c1, av[rt]);
    }
#pragma unroll
    for (int rt = 0; rt < 4; ++rt)
#pragma unroll
      for (int r = 0; r < 4; ++r) z[rt * 4 + r] += EXP2(av[rt][r]);
  }
#pragma unroll
  for (int off = 1; off < 16; off <<= 1) {
#pragma unroll
    for (int i = 0; i < 16; ++i) z[i] += __shfl_xor(z[i], off);
  }
  if (l == 0) {
#pragma unroll
    for (int rt = 0; rt < 4; ++rt)
#pragma unroll
      for (int r = 0; r < 4; ++r)
        atomicAdd(&zrow[rt * 16 + quad * 4 + r], z[rt * 4 + r]);
  }
  __syncthreads();  // zrow complete
  if (tid < 64) lse[bh * 1024 + r0 + tid] = __log2f(zrow[tid]);
  float nlb[16];  // -log2(Z)
#pragma unroll
  for (int rt = 0; rt < 4; ++rt)
#pragma unroll
    for (int r = 0; r < 4; ++r)
      nlb[rt * 4 + r] = -__log2f(zrow[rt * 16 + quad * 4 + r]);

  // ---- pass 2: column sums of p and p*log2p ----
  // d = score + (-log2 Z); p = exp2(d); cs += p; cp += p*d. 4 VALU/element.
  for (int s = 0; s < 8; ++s) {
    const bf16x8 c0 = kf0, c1 = kf1;
    if (s < 7) {
      kf0 = *(const bf16x8*)(kfrag + (size_t)(s + 1) * 8192);
      kf1 = *(const bf16x8*)(kfrag + (size_t)(s + 1) * 8192 + 32);
    }
    f32x4 av[4];
#pragma unroll
    for (int rt = 0; rt < 4; ++rt) {
      av[rt] = MFMA16(aq0[rt], c0, zero);
      av[rt] = MFMA16(aq1[rt], c1, av[rt]);
    }
    float cs = 0.f, cp = 0.f;
#pragma unroll
    for (int rt = 0; rt < 4; ++rt) {
#pragma unroll
      for (int r = 0; r < 4; ++r) {
        const float d = av[rt][r] + nlb[rt * 4 + r];
        const float t = EXP2(d);
        cs += t;
        cp = fmaf(t, d, cp);
      }
    }
    cs += __shfl_xor(cs, 16); cs += __shfl_xor(cs, 32);
    cp += __shfl_xor(cp, 16); cp += __shfl_xor(cp, 32);
    if (lane < 16) {  // wave-private columns: plain LDS accumulate
      sS[s * 128 + w * 16 + l] += cs;
      sP[s * 128 + w * 16 + l] += cp;
    }
  }
  __syncthreads();
  for (int i = tid; i < 1024; i += 512) {
    atomicAdd(&colSP[i], sS[i]);
    atomicAdd(&colSP[1024 + i], sP[i]);
  }

  // ---- fused mask: last block to finish computes mask/keepCnt ----
  __threadfence();  // order colSP atomics before done increment
  if (tid == 0) lastBlk = (atomicAdd(done, 1u) == 767u) ? 1 : 0;
  __syncthreads();
  if (!lastBlk) return;
  __threadfence();  // acquire: all blocks' colSP writes visible
  const int ce = cur_epoch[0];
  float factor = 0.f;
  for (int i = 1; i <= ce; ++i) factor += __expf(-(float)i);
  factor *= 5.0f;
  const float thr = __logf(768.0f) - factor;
  for (int j = tid; j < 1024; j += 512) {
    const float s  = __hip_atomic_load(&colSP[j], __ATOMIC_RELAXED, __HIP_MEMORY_SCOPE_AGENT);
    const float pl = __hip_atomic_load(&colSP[1024 + j], __ATOMIC_RELAXED, __HIP_MEMORY_SCOPE_AGENT) * LN2;
    const float ent = __logf(s) - pl / s;
    const int keep = (ent <= thr) ? 1 : 0;
    mask[j] = keep ? 1.0f : 0.0f;
    if (keep) atomicAdd(keepCnt, 1);
  }
}

// --- 5. masked AV -> ctxb (bf16). q pre-scaled; lse in log2 domain. --------
__global__ __launch_bounds__(256) void k_av(
    const __bf16* __restrict__ qb, const __bf16* __restrict__ kb,
    const float* __restrict__ v, const float* __restrict__ lse,
    const float* __restrict__ mask, const int* __restrict__ keepCnt,
    __bf16* __restrict__ ctxb)
{
  if (*keepCnt == 0) return;  // ctxb unused downstream in this case
  const int tid = threadIdx.x;
  const int bh = blockIdx.x, r0 = blockIdx.y * 32;
  const int b_ = bh / 12, h = bh % 12;
  __shared__ float qs[32][64];
  __shared__ float pbuf[4][8][64];
  for (int i = tid; i < 2048; i += 256)
    qs[i >> 6][i & 63] = (float)qb[((size_t)bh * 1024 + r0) * 64 + i];
  __syncthreads();
  const int w = tid >> 6, l = tid & 63, rb = w * 8;
  float ls[8];
#pragma unroll
  for (int i = 0; i < 8; ++i) ls[i] = lse[bh * 1024 + r0 + rb + i];
  float acc[8] = {};
  for (int chunk = 0; chunk < 16; ++chunk) {
    const float mk = mask[chunk * 64 + l];
    if (__ballot(mk != 0.0f) == 0ull) continue;  // block-uniform
    const __bf16* kp = kb + ((size_t)bh * 1024 + chunk * 64 + l) * 64;
    float s[8] = {};
    for (int d0 = 0; d0 < 64; d0 += 8) {
      const bf16x8 kf = *(const bf16x8*)(kp + d0);
#pragma unroll
      for (int dd = 0; dd < 8; ++dd) {
        const float kv = (float)kf[dd];
#pragma unroll
        for (int i = 0; i < 8; ++i) s[i] += qs[rb + i][d0 + dd] * kv;
      }
    }
    __syncthreads();
#pragma unroll
    for (int i = 0; i < 8; ++i)
      pbuf[w][i][l] = EXP2(s[i] - ls[i]) * mk;
    __syncthreads();
    const float* vp = v + ((size_t)bh * 1024 + chunk * 64) * 64 + l;
    for (int jj = 0; jj < 64; ++jj) {
      const float vv = vp[(size_t)jj * 64];
#pragma unroll
      for (int i = 0; i < 8; ++i) acc[i] += pbuf[w][i][jj] * vv;
    }
  }
#pragma unroll
  for (int i = 0; i < 8; ++i)
    ctxb[((size_t)(b_ * 1024 + r0 + rb + i)) * 768 + h * 64 + l] = (__bf16)acc[i];
}

// --- 6. proj GEMM: out = ctxb @ pwb.T + bias; bias-only when keep==0 -------
__global__ __launch_bounds__(256) void kg_proj(
    const __bf16* __restrict__ A, const __bf16* __restrict__ Bm,
    const float* __restrict__ bias, const int* __restrict__ keepCnt,
    float* __restrict__ out)
{
  const int tid = threadIdx.x;
  const int w = tid >> 6, lane = tid & 63, quad = lane >> 4, l = lane & 15;
  const int r0 = blockIdx.y * 64, c0 = blockIdx.x * 64;
  if (*keepCnt == 0) {  // ctx == 0 -> out = bias (uniform branch)
#pragma unroll
    for (int ct = 0; ct < 4; ++ct) {
      const int c = c0 + ct * 16 + l;
      const float bv = bias[c];
#pragma unroll
      for (int i = 0; i < 4; ++i) {
        const int rg = r0 + w * 16 + quad * 4 + i;
        out[(size_t)rg * 768 + c] = bv;
      }
    }
    return;
  }
  __shared__ __bf16 As[64 * 72];
  __shared__ __bf16 Bs[64 * 72];
  const int row = tid >> 3, ko = (tid & 7) * 8;
  const f32x4 zero = {0.f, 0.f, 0.f, 0.f};
  f32x4 acc[4];
#pragma unroll
  for (int ct = 0; ct < 4; ++ct) acc[ct] = zero;

  uint4 a0 = *(const uint4*)(A + (size_t)(r0 + row) * 768 + ko);
  uint4 a1 = *(const uint4*)(A + (size_t)(r0 + row + 32) * 768 + ko);
  uint4 b0 = *(const uint4*)(Bm + (size_t)(c0 + row) * 768 + ko);
  uint4 b1 = *(const uint4*)(Bm + (size_t)(c0 + row + 32) * 768 + ko);

  for (int k0 = 0; k0 < 768; k0 += 64) {
    __syncthreads();
    *(uint4*)&As[row * 72 + ko] = a0;
    *(uint4*)&As[(row + 32) * 72 + ko] = a1;
    *(uint4*)&Bs[row * 72 + ko] = b0;
    *(uint4*)&Bs[(row + 32) * 72 + ko] = b1;
    __syncthreads();
    if (k0 < 704) {
      a0 = *(const uint4*)(A + (size_t)(r0 + row) * 768 + k0 + 64 + ko);
      a1 = *(const uint4*)(A + (size_t)(r0 + row + 32) * 768 + k0 + 64 + ko);
      b0 = *(const uint4*)(Bm + (size_t)(c0 + row) * 768 + k0 + 64 + ko);
      b1 = *(const uint4*)(Bm + (size_t)(c0 + row + 32) * 768 + k0 + 64 + ko);
    }
    const bf16x8 af0 = *(const bf16x8*)&As[(w * 16 + l) * 72 + quad * 8];
    const bf16x8 af1 = *(const bf16x8*)&As[(w * 16 + l) * 72 + 32 + quad * 8];
#pragma unroll
    for (int ct = 0; ct < 4; ++ct) {
      const bf16x8 bf0 = *(const bf16x8*)&Bs[(ct * 16 + l) * 72 + quad * 8];
      const bf16x8 bf1 = *(const bf16x8*)&Bs[(ct * 16 + l) * 72 + 32 + quad * 8];
      acc[ct] = MFMA16(af0, bf0, acc[ct]);
      acc[ct] = MFMA16(af1, bf1, acc[ct]);
    }
  }
#pragma unroll
  for (int ct = 0; ct < 4; ++ct) {
    const int c = c0 + ct * 16 + l;
#pragma unroll
    for (int i = 0; i < 4; ++i) {
      const int rg = r0 + w * 16 + quad * 4 + i;
      out[(size_t)rg * 768 + c] = acc[ct][i] + bias[c];
    }
  }
}

extern "C" void kernel_launch(void* const* d_in, const int* in_sizes, int n_in,
                              void* d_out, int out_size, void* d_ws, size_t ws_size,
                              hipStream_t stream)
{
  const float* x      = (const float*)d_in[0];
  const float* qkv_w  = (const float*)d_in[1];
  const float* proj_w = (const float*)d_in[2];
  const float* proj_b = (const float*)d_in[3];
  const int*   cur_ep = (const int*)d_in[4];

  char* W = (char*)d_ws;
  __bf16* xb    = (__bf16*)(W + 0);
  __bf16* qwb   = (__bf16*)(W + 6291456);
  __bf16* pwb   = (__bf16*)(W + 9830400);
  __bf16* qb    = (__bf16*)(W + 11010048);
  __bf16* kb    = (__bf16*)(W + 17301504);
  float*  v     = (float*) (W + 23592960);
  __bf16* ctxb  = (__bf16*)(W + 36175872);
  float*  lse   = (float*) (W + 42467328);
  float*  mask  = (float*) (W + 42663936);
  int*    keep  = (int*)   (W + 42668032);
  unsigned int* done = (unsigned int*)(W + 42668036);
  float*  colSP = (float*) (W + 42668544);
  float*  out   = (float*)d_out;

  kc_conv<<<5376, 256, 0, stream>>>(x, qkv_w, proj_w, xb, qwb, pwb, colSP, keep, done);
  kg_qkv<<<dim3(18, 32), 256, 0, stream>>>(xb, qwb, qb, kb, v);
  ks_fused<<<dim3(48, 16), 512, 0, stream>>>(qb, kb, lse, colSP, cur_ep, mask, keep, done);
  k_av<<<dim3(48, 32), 256, 0, stream>>>(qb, kb, v, lse, mask, keep, ctxb);
  kg_proj<<<dim3(12, 64), 256, 0, stream>>>(ctxb, pwb, proj_b, keep, out);
}

// Round 9
// 160.057 us; speedup vs baseline: 1.4788x; 1.4788x over previous
//
#include <hip/hip_runtime.h>

// ---------------------------------------------------------------------------
// EntropyPrunedSelfAttention  (B=4, N=1024, C=768, H=12, hd=64)
// Round 20: un-contaminate ks_fused. R6/R8 proved the fused mask tail wrecks
// ks_fused codegen (VGPR 56->48, prefetch sunk, 48->130us, VALUBusy 10%).
// ks_fused is now byte-for-byte the R4/R15 kernel (proven 48us). The k_mask
// launch is removed differently: k_av and kg_proj each recompute the mask /
// keep-any flag from colSP in a trivial prologue (L2-hot 8KB read + 1024
// logs per block). 5 launches total; ks_fused untouched.
//
// Workspace (byte offsets):
//   xb      bf16[4096*768]      @ 0
//   qwb     bf16[2304*768]      @ 6291456
//   pwb     bf16[768*768]       @ 9830400
//   qb      bf16[48*1024*64]    @ 11010048   (pre-scaled by 0.125*log2e)
//   kb      bf16[48*1024*64]    @ 17301504
//   v       f32 [48*1024*64]    @ 23592960
//   ctxb    bf16[4096*768]      @ 36175872
//   lse     f32 [48*1024]       @ 42467328   (log2 of row-sum Z)
//   colSP   f32 [2048]          @ 42668544   (colS[1024] ++ colP_log2[1024])
// total ~42.7 MB
// ---------------------------------------------------------------------------

typedef __bf16 bf16x8 __attribute__((ext_vector_type(8)));
typedef __bf16 bf16x4 __attribute__((ext_vector_type(4)));
typedef float  f32x4  __attribute__((ext_vector_type(4)));

#define MFMA16(a, b, c) __builtin_amdgcn_mfma_f32_16x16x32_bf16((a), (b), (c), 0, 0, 0)
#define QSCALE 0.18033688f   /* 0.125 * log2(e) */
#define LN2    0.69314718f

#if __has_builtin(__builtin_amdgcn_exp2f)
#define EXP2(x) __builtin_amdgcn_exp2f(x)
#else
#define EXP2(x) exp2f(x)
#endif

__device__ __forceinline__ void ld_glds16(const __bf16* g, __bf16* s) {
  __builtin_amdgcn_global_load_lds(
      (const __attribute__((address_space(1))) unsigned int*)g,
      (__attribute__((address_space(3))) unsigned int*)s, 16, 0, 0);
}

// --- 1. fp32 -> bf16 conversion + zero colSP -------------------------------
__global__ __launch_bounds__(256) void kc_conv(
    const float* __restrict__ x, const float* __restrict__ qw, const float* __restrict__ pw,
    __bf16* __restrict__ xb, __bf16* __restrict__ qwb, __bf16* __restrict__ pwb,
    float* __restrict__ colSP)
{
  const int i = blockIdx.x * 256 + threadIdx.x;
  const float4* src;
  __bf16* dst;
  int j;
  if (i < 786432)       { src = (const float4*)x;  dst = xb;  j = i; }
  else if (i < 1228800) { src = (const float4*)qw; dst = qwb; j = i - 786432; }
  else                  { src = (const float4*)pw; dst = pwb; j = i - 1228800; }
  const float4 f = src[j];
  bf16x4 o;
  o[0] = (__bf16)f.x; o[1] = (__bf16)f.y; o[2] = (__bf16)f.z; o[3] = (__bf16)f.w;
  *(bf16x4*)(dst + 4 * (size_t)j) = o;
  if (i < 2048) colSP[i] = 0.f;
}

// --- 2. QKV GEMM, m97-style. Q part written pre-scaled by QSCALE. ----------
__global__ __launch_bounds__(256) void kg_qkv(
    const __bf16* __restrict__ A, const __bf16* __restrict__ Bm,
    __bf16* __restrict__ qb, __bf16* __restrict__ kb, float* __restrict__ v)
{
  __shared__ __bf16 As[128 * 64];
  __shared__ __bf16 Bs[128 * 64];
  const int tid = threadIdx.x;
  const int w = tid >> 6, lane = tid & 63, quad = lane >> 4, l = lane & 15;
  const int wm = w >> 1, wn = w & 1;
  const int r0 = blockIdx.y * 128, c0 = blockIdx.x * 128;
  const int srow = lane >> 3, skk = (lane & 7) * 8;

  f32x4 acc[4][4] = {};

  for (int k0 = 0; k0 < 768; k0 += 64) {
    if (k0) __syncthreads();
#pragma unroll
    for (int s = 0; s < 4; ++s) {
      const int si = w * 4 + s;               // 0..15
      const int row = si * 8 + srow;
      ld_glds16(A + (size_t)(r0 + row) * 768 + k0 + skk, &As[si * 512]);
      ld_glds16(Bm + (size_t)(c0 + row) * 768 + k0 + skk, &Bs[si * 512]);
    }
    __syncthreads();
#pragma unroll
    for (int kk = 0; kk < 2; ++kk) {
      bf16x8 af[4], bf[4];
#pragma unroll
      for (int t = 0; t < 4; ++t) {
        af[t] = *(const bf16x8*)&As[(wm * 64 + t * 16 + l) * 64 + kk * 32 + quad * 8];
        bf[t] = *(const bf16x8*)&Bs[(wn * 64 + t * 16 + l) * 64 + kk * 32 + quad * 8];
      }
#pragma unroll
      for (int mt = 0; mt < 4; ++mt)
#pragma unroll
        for (int nt = 0; nt < 4; ++nt)
          acc[mt][nt] = MFMA16(af[mt], bf[nt], acc[mt][nt]);
    }
  }

  const int part = c0 / 768;
  const int cbase = c0 % 768;
#pragma unroll
  for (int mt = 0; mt < 4; ++mt) {
#pragma unroll
    for (int nt = 0; nt < 4; ++nt) {
      const int cc = cbase + wn * 64 + nt * 16 + l;  // 0..767
      const int h = cc >> 6, d = cc & 63;
#pragma unroll
      for (int i = 0; i < 4; ++i) {
        const int rg = r0 + wm * 64 + mt * 16 + quad * 4 + i;
        const int b_ = rg >> 10, n = rg & 1023;
        const size_t off = ((size_t)(b_ * 12 + h) * 1024 + n) * 64 + d;
        const float val = acc[mt][nt][i];
        if (part == 0)      qb[off] = (__bf16)(val * QSCALE);
        else if (part == 1) kb[off] = (__bf16)val;
        else                v[off]  = val;
      }
    }
  }
}

// --- 3. fused stats — byte-for-byte the R4/R15 kernel (proven 48us) --------
// grid (48, 16), 512 threads (8 waves). Block = (bh, 64 rows) x 1024 cols.
// Chunk = 128 K-rows; wave w owns cols s*128 + w*16 + l. Per wave per chunk:
// 2 global dwordx4 (depth-1 prefetch), 8 MFMA batched, then 16 exp2 batched.
__global__ __launch_bounds__(512) void ks_fused(
    const __bf16* __restrict__ qb, const __bf16* __restrict__ kb,
    float* __restrict__ lse, float* __restrict__ colSP)
{
  __shared__ float sS[1024];
  __shared__ float sP[1024];
  __shared__ float zrow[64];
  const int tid = threadIdx.x;
  const int w = tid >> 6, lane = tid & 63, quad = lane >> 4, l = lane & 15;
  const int bh = blockIdx.x, r0 = blockIdx.y * 64;
  for (int i = tid; i < 1024; i += 512) { sS[i] = 0.f; sP[i] = 0.f; }
  if (tid < 64) zrow[tid] = 0.f;
  __syncthreads();  // init visible

  // Q fragments (pre-scaled): rows r0 + rt*16 + l, dims quad*8 (+0 / +32)
  const __bf16* qbase = qb + ((size_t)bh * 1024 + r0 + l) * 64;
  bf16x8 aq0[4], aq1[4];
#pragma unroll
  for (int rt = 0; rt < 4; ++rt) {
    aq0[rt] = *(const bf16x8*)(qbase + rt * 1024 + quad * 8);
    aq1[rt] = *(const bf16x8*)(qbase + rt * 1024 + 32 + quad * 8);
  }
  // K fragment base: row (w*16 + l), dim quad*8; chunk s adds s*128*64 elems.
  const __bf16* kfrag = kb + (size_t)bh * 65536 + (size_t)(w * 16 + l) * 64 + quad * 8;
  const f32x4 zero = {0.f, 0.f, 0.f, 0.f};

  bf16x8 kf0 = *(const bf16x8*)(kfrag);
  bf16x8 kf1 = *(const bf16x8*)(kfrag + 32);

  float z[16] = {};
  // ---- pass 1: row sums of exp2(score) ----
  for (int s = 0; s < 8; ++s) {
    const bf16x8 c0 = kf0, c1 = kf1;
    const int nxt = (s + 1) & 7;  // s==7 prefetches chunk 0 for pass 2
    kf0 = *(const bf16x8*)(kfrag + (size_t)nxt * 8192);
    kf1 = *(const bf16x8*)(kfrag + (size_t)nxt * 8192 + 32);
    f32x4 av[4];
#pragma unroll
    for (int rt = 0; rt < 4; ++rt) {
      av[rt] = MFMA16(aq0[rt], c0, zero);
      av[rt] = MFMA16(aq1[rt], c1, av[rt]);
    }
#pragma unroll
    for (int rt = 0; rt < 4; ++rt)
#pragma unroll
      for (int r = 0; r < 4; ++r) z[rt * 4 + r] += exp2f(av[rt][r]);
  }
#pragma unroll
  for (int off = 1; off < 16; off <<= 1) {
#pragma unroll
    for (int i = 0; i < 16; ++i) z[i] += __shfl_xor(z[i], off);
  }
  if (l == 0) {
#pragma unroll
    for (int rt = 0; rt < 4; ++rt)
#pragma unroll
      for (int r = 0; r < 4; ++r)
        atomicAdd(&zrow[rt * 16 + quad * 4 + r], z[rt * 4 + r]);
  }
  __syncthreads();  // zrow complete
  if (tid < 64) lse[bh * 1024 + r0 + tid] = __log2f(zrow[tid]);
  float nlb[16];  // -log2(Z)
#pragma unroll
  for (int rt = 0; rt < 4; ++rt)
#pragma unroll
    for (int r = 0; r < 4; ++r)
      nlb[rt * 4 + r] = -__log2f(zrow[rt * 16 + quad * 4 + r]);

  // ---- pass 2: column sums of p and p*log2p ----
  // d = score + (-log2 Z); p = exp2(d); cs += p; cp += p*d. 4 VALU/element.
  for (int s = 0; s < 8; ++s) {
    const bf16x8 c0 = kf0, c1 = kf1;
    if (s < 7) {
      kf0 = *(const bf16x8*)(kfrag + (size_t)(s + 1) * 8192);
      kf1 = *(const bf16x8*)(kfrag + (size_t)(s + 1) * 8192 + 32);
    }
    f32x4 av[4];
#pragma unroll
    for (int rt = 0; rt < 4; ++rt) {
      av[rt] = MFMA16(aq0[rt], c0, zero);
      av[rt] = MFMA16(aq1[rt], c1, av[rt]);
    }
    float cs = 0.f, cp = 0.f;
#pragma unroll
    for (int rt = 0; rt < 4; ++rt) {
#pragma unroll
      for (int r = 0; r < 4; ++r) {
        const float d = av[rt][r] + nlb[rt * 4 + r];
        const float t = exp2f(d);
        cs += t;
        cp = fmaf(t, d, cp);
      }
    }
    cs += __shfl_xor(cs, 16); cs += __shfl_xor(cs, 32);
    cp += __shfl_xor(cp, 16); cp += __shfl_xor(cp, 32);
    if (lane < 16) {  // wave-private columns: plain LDS accumulate
      sS[s * 128 + w * 16 + l] += cs;
      sP[s * 128 + w * 16 + l] += cp;
    }
  }
  __syncthreads();
  for (int i = tid; i < 1024; i += 512) {
    atomicAdd(&colSP[i], sS[i]);
    atomicAdd(&colSP[1024 + i], sP[i]);
  }
}

// --- 5. masked AV -> ctxb. Mask recomputed locally from colSP. -------------
__global__ __launch_bounds__(256) void k_av(
    const __bf16* __restrict__ qb, const __bf16* __restrict__ kb,
    const float* __restrict__ v, const float* __restrict__ lse,
    const float* __restrict__ colSP, const int* __restrict__ cur_epoch,
    __bf16* __restrict__ ctxb)
{
  const int tid = threadIdx.x;
  const int bh = blockIdx.x, r0 = blockIdx.y * 32;
  const int b_ = bh / 12, h = bh % 12;
  __shared__ float qs[32][64];
  __shared__ float pbuf[4][8][64];
  __shared__ float maskS[1024];
  __shared__ int anyKeep;
  if (tid == 0) anyKeep = 0;
  __syncthreads();
  // mask prologue: thr from cur_epoch; entropy per column from colSP (L2-hot)
  {
    const int ce = cur_epoch[0];
    float factor = 0.f;
    for (int i = 1; i <= ce; ++i) factor += __expf(-(float)i);
    factor *= 5.0f;
    const float thr = __logf(768.0f) - factor;
    for (int j = tid; j < 1024; j += 256) {
      const float s = colSP[j];
      const float ent = __logf(s) - (colSP[1024 + j] * LN2) / s;
      const int keep = (ent <= thr) ? 1 : 0;
      maskS[j] = keep ? 1.0f : 0.0f;
      if (keep) anyKeep = 1;  // benign race: all writers store 1
    }
  }
  for (int i = tid; i < 2048; i += 256)
    qs[i >> 6][i & 63] = (float)qb[((size_t)bh * 1024 + r0) * 64 + i];
  __syncthreads();
  if (anyKeep == 0) return;  // ctxb unused downstream in this case
  const int w = tid >> 6, l = tid & 63, rb = w * 8;
  float ls[8];
#pragma unroll
  for (int i = 0; i < 8; ++i) ls[i] = lse[bh * 1024 + r0 + rb + i];
  float acc[8] = {};
  for (int chunk = 0; chunk < 16; ++chunk) {
    const float mk = maskS[chunk * 64 + l];
    if (__ballot(mk != 0.0f) == 0ull) continue;  // block-uniform
    const __bf16* kp = kb + ((size_t)bh * 1024 + chunk * 64 + l) * 64;
    float s[8] = {};
    for (int d0 = 0; d0 < 64; d0 += 8) {
      const bf16x8 kf = *(const bf16x8*)(kp + d0);
#pragma unroll
      for (int dd = 0; dd < 8; ++dd) {
        const float kv = (float)kf[dd];
#pragma unroll
        for (int i = 0; i < 8; ++i) s[i] += qs[rb + i][d0 + dd] * kv;
      }
    }
    __syncthreads();
#pragma unroll
    for (int i = 0; i < 8; ++i)
      pbuf[w][i][l] = EXP2(s[i] - ls[i]) * mk;
    __syncthreads();
    const float* vp = v + ((size_t)bh * 1024 + chunk * 64) * 64 + l;
    for (int jj = 0; jj < 64; ++jj) {
      const float vv = vp[(size_t)jj * 64];
#pragma unroll
      for (int i = 0; i < 8; ++i) acc[i] += pbuf[w][i][jj] * vv;
    }
  }
#pragma unroll
  for (int i = 0; i < 8; ++i)
    ctxb[((size_t)(b_ * 1024 + r0 + rb + i)) * 768 + h * 64 + l] = (__bf16)acc[i];
}

// --- 6. proj GEMM: out = ctxb @ pwb.T + bias; keep-any recomputed. ---------
__global__ __launch_bounds__(256) void kg_proj(
    const __bf16* __restrict__ A, const __bf16* __restrict__ Bm,
    const float* __restrict__ bias, const float* __restrict__ colSP,
    const int* __restrict__ cur_epoch, float* __restrict__ out)
{
  const int tid = threadIdx.x;
  const int w = tid >> 6, lane = tid & 63, quad = lane >> 4, l = lane & 15;
  const int r0 = blockIdx.y * 64, c0 = blockIdx.x * 64;
  __shared__ int anyKeep;
  if (tid == 0) anyKeep = 0;
  __syncthreads();
  {
    const int ce = cur_epoch[0];
    float factor = 0.f;
    for (int i = 1; i <= ce; ++i) factor += __expf(-(float)i);
    factor *= 5.0f;
    const float thr = __logf(768.0f) - factor;
    for (int j = tid; j < 1024; j += 256) {
      const float s = colSP[j];
      const float ent = __logf(s) - (colSP[1024 + j] * LN2) / s;
      if (ent <= thr) anyKeep = 1;  // benign race
    }
  }
  __syncthreads();
  if (anyKeep == 0) {  // ctx == 0 -> out = bias (uniform branch)
#pragma unroll
    for (int ct = 0; ct < 4; ++ct) {
      const int c = c0 + ct * 16 + l;
      const float bv = bias[c];
#pragma unroll
      for (int i = 0; i < 4; ++i) {
        const int rg = r0 + w * 16 + quad * 4 + i;
        out[(size_t)rg * 768 + c] = bv;
      }
    }
    return;
  }
  __shared__ __bf16 As[64 * 72];
  __shared__ __bf16 Bs[64 * 72];
  const int row = tid >> 3, ko = (tid & 7) * 8;
  const f32x4 zero = {0.f, 0.f, 0.f, 0.f};
  f32x4 acc[4];
#pragma unroll
  for (int ct = 0; ct < 4; ++ct) acc[ct] = zero;

  uint4 a0 = *(const uint4*)(A + (size_t)(r0 + row) * 768 + ko);
  uint4 a1 = *(const uint4*)(A + (size_t)(r0 + row + 32) * 768 + ko);
  uint4 b0 = *(const uint4*)(Bm + (size_t)(c0 + row) * 768 + ko);
  uint4 b1 = *(const uint4*)(Bm + (size_t)(c0 + row + 32) * 768 + ko);

  for (int k0 = 0; k0 < 768; k0 += 64) {
    __syncthreads();
    *(uint4*)&As[row * 72 + ko] = a0;
    *(uint4*)&As[(row + 32) * 72 + ko] = a1;
    *(uint4*)&Bs[row * 72 + ko] = b0;
    *(uint4*)&Bs[(row + 32) * 72 + ko] = b1;
    __syncthreads();
    if (k0 < 704) {
      a0 = *(const uint4*)(A + (size_t)(r0 + row) * 768 + k0 + 64 + ko);
      a1 = *(const uint4*)(A + (size_t)(r0 + row + 32) * 768 + k0 + 64 + ko);
      b0 = *(const uint4*)(Bm + (size_t)(c0 + row) * 768 + k0 + 64 + ko);
      b1 = *(const uint4*)(Bm + (size_t)(c0 + row + 32) * 768 + k0 + 64 + ko);
    }
    const bf16x8 af0 = *(const bf16x8*)&As[(w * 16 + l) * 72 + quad * 8];
    const bf16x8 af1 = *(const bf16x8*)&As[(w * 16 + l) * 72 + 32 + quad * 8];
#pragma unroll
    for (int ct = 0; ct < 4; ++ct) {
      const bf16x8 bf0 = *(const bf16x8*)&Bs[(ct * 16 + l) * 72 + quad * 8];
      const bf16x8 bf1 = *(const bf16x8*)&Bs[(ct * 16 + l) * 72 + 32 + quad * 8];
      acc[ct] = MFMA16(af0, bf0, acc[ct]);
      acc[ct] = MFMA16(af1, bf1, acc[ct]);
    }
  }
#pragma unroll
  for (int ct = 0; ct < 4; ++ct) {
    const int c = c0 + ct * 16 + l;
#pragma unroll
    for (int i = 0; i < 4; ++i) {
      const int rg = r0 + w * 16 + quad * 4 + i;
      out[(size_t)rg * 768 + c] = acc[ct][i] + bias[c];
    }
  }
}

extern "C" void kernel_launch(void* const* d_in, const int* in_sizes, int n_in,
                              void* d_out, int out_size, void* d_ws, size_t ws_size,
                              hipStream_t stream)
{
  const float* x      = (const float*)d_in[0];
  const float* qkv_w  = (const float*)d_in[1];
  const float* proj_w = (const float*)d_in[2];
  const float* proj_b = (const float*)d_in[3];
  const int*   cur_ep = (const int*)d_in[4];

  char* W = (char*)d_ws;
  __bf16* xb    = (__bf16*)(W + 0);
  __bf16* qwb   = (__bf16*)(W + 6291456);
  __bf16* pwb   = (__bf16*)(W + 9830400);
  __bf16* qb    = (__bf16*)(W + 11010048);
  __bf16* kb    = (__bf16*)(W + 17301504);
  float*  v     = (float*) (W + 23592960);
  __bf16* ctxb  = (__bf16*)(W + 36175872);
  float*  lse   = (float*) (W + 42467328);
  float*  colSP = (float*) (W + 42668544);
  float*  out   = (float*)d_out;

  kc_conv<<<5376, 256, 0, stream>>>(x, qkv_w, proj_w, xb, qwb, pwb, colSP);
  kg_qkv<<<dim3(18, 32), 256, 0, stream>>>(xb, qwb, qb, kb, v);
  ks_fused<<<dim3(48, 16), 512, 0, stream>>>(qb, kb, lse, colSP);
  k_av<<<dim3(48, 32), 256, 0, stream>>>(qb, kb, v, lse, colSP, cur_ep, ctxb);
  kg_proj<<<dim3(12, 64), 256, 0, stream>>>(ctxb, pwb, proj_b, colSP, cur_ep, out);
}

// Round 10
// 158.860 us; speedup vs baseline: 1.4900x; 1.0075x over previous
//
#include <hip/hip_runtime.h>

// ---------------------------------------------------------------------------
// EntropyPrunedSelfAttention  (B=4, N=1024, C=768, H=12, hd=64)
// Round 21: kg_qkv re-tiled 128x128 -> 128x64. Old grid 576 blocks = 2.25
// blocks/CU (latency-bound regime, m102 curve); new grid (36,32) = 1152
// blocks = 4.5/CU. Staging: As 16KB (4 insts/wave) + Bs 8KB (2 insts/wave)
// per BK=64 step; per-wave output 64x32 (4x2 16^2 tiles, acc 32 VGPR).
// k_av: early-out moved before qs staging. ks_fused: byte-identical to R4.
//
// Workspace (byte offsets):
//   xb      bf16[4096*768]      @ 0
//   qwb     bf16[2304*768]      @ 6291456
//   pwb     bf16[768*768]       @ 9830400
//   qb      bf16[48*1024*64]    @ 11010048   (pre-scaled by 0.125*log2e)
//   kb      bf16[48*1024*64]    @ 17301504
//   v       f32 [48*1024*64]    @ 23592960
//   ctxb    bf16[4096*768]      @ 36175872
//   lse     f32 [48*1024]       @ 42467328   (log2 of row-sum Z)
//   colSP   f32 [2048]          @ 42668544   (colS[1024] ++ colP_log2[1024])
// total ~42.7 MB
// ---------------------------------------------------------------------------

typedef __bf16 bf16x8 __attribute__((ext_vector_type(8)));
typedef __bf16 bf16x4 __attribute__((ext_vector_type(4)));
typedef float  f32x4  __attribute__((ext_vector_type(4)));

#define MFMA16(a, b, c) __builtin_amdgcn_mfma_f32_16x16x32_bf16((a), (b), (c), 0, 0, 0)
#define QSCALE 0.18033688f   /* 0.125 * log2(e) */
#define LN2    0.69314718f

#if __has_builtin(__builtin_amdgcn_exp2f)
#define EXP2(x) __builtin_amdgcn_exp2f(x)
#else
#define EXP2(x) exp2f(x)
#endif

__device__ __forceinline__ void ld_glds16(const __bf16* g, __bf16* s) {
  __builtin_amdgcn_global_load_lds(
      (const __attribute__((address_space(1))) unsigned int*)g,
      (__attribute__((address_space(3))) unsigned int*)s, 16, 0, 0);
}

// --- 1. fp32 -> bf16 conversion + zero colSP -------------------------------
__global__ __launch_bounds__(256) void kc_conv(
    const float* __restrict__ x, const float* __restrict__ qw, const float* __restrict__ pw,
    __bf16* __restrict__ xb, __bf16* __restrict__ qwb, __bf16* __restrict__ pwb,
    float* __restrict__ colSP)
{
  const int i = blockIdx.x * 256 + threadIdx.x;
  const float4* src;
  __bf16* dst;
  int j;
  if (i < 786432)       { src = (const float4*)x;  dst = xb;  j = i; }
  else if (i < 1228800) { src = (const float4*)qw; dst = qwb; j = i - 786432; }
  else                  { src = (const float4*)pw; dst = pwb; j = i - 1228800; }
  const float4 f = src[j];
  bf16x4 o;
  o[0] = (__bf16)f.x; o[1] = (__bf16)f.y; o[2] = (__bf16)f.z; o[3] = (__bf16)f.w;
  *(bf16x4*)(dst + 4 * (size_t)j) = o;
  if (i < 2048) colSP[i] = 0.f;
}

// --- 2. QKV GEMM: 128x64 tile, grid (36,32) = 1152 blocks = 4.5/CU ---------
// Wave (wm,wn) owns a 64x32 patch (4x2 of 16x16). BK=64. Per wave per step:
// 4 A-insts + 2 B-insts (global_load_lds 16B), 12 ds_read_b128, 16 MFMA.
__global__ __launch_bounds__(256) void kg_qkv(
    const __bf16* __restrict__ A, const __bf16* __restrict__ Bm,
    __bf16* __restrict__ qb, __bf16* __restrict__ kb, float* __restrict__ v)
{
  __shared__ __bf16 As[128 * 64];   // 16 KB
  __shared__ __bf16 Bs[64 * 64];    // 8 KB
  const int tid = threadIdx.x;
  const int w = tid >> 6, lane = tid & 63, quad = lane >> 4, l = lane & 15;
  const int wm = w >> 1, wn = w & 1;
  const int r0 = blockIdx.y * 128, c0 = blockIdx.x * 64;
  // staging: one wave-inst covers 8 rows x 64 cols (1KB). lane -> row si*8 +
  // (lane>>3), col-octet (lane&7)*8; LDS linear offset = lane*8 elems. 
  const int srow = lane >> 3, skk = (lane & 7) * 8;

  f32x4 acc[4][2] = {};

  for (int k0 = 0; k0 < 768; k0 += 64) {
    if (k0) __syncthreads();  // previous compute done -> LDS writable
#pragma unroll
    for (int s = 0; s < 4; ++s) {
      const int si = w * 4 + s;               // 0..15 -> A rows 0..127
      ld_glds16(A + (size_t)(r0 + si * 8 + srow) * 768 + k0 + skk, &As[si * 512]);
    }
#pragma unroll
    for (int s = 0; s < 2; ++s) {
      const int sj = w * 2 + s;               // 0..7  -> B rows 0..63
      ld_glds16(Bm + (size_t)(c0 + sj * 8 + srow) * 768 + k0 + skk, &Bs[sj * 512]);
    }
    __syncthreads();  // drains vmcnt -> staged tiles visible
#pragma unroll
    for (int kk = 0; kk < 2; ++kk) {
      bf16x8 af[4], bf[2];
#pragma unroll
      for (int t = 0; t < 4; ++t)
        af[t] = *(const bf16x8*)&As[(wm * 64 + t * 16 + l) * 64 + kk * 32 + quad * 8];
#pragma unroll
      for (int t = 0; t < 2; ++t)
        bf[t] = *(const bf16x8*)&Bs[(wn * 32 + t * 16 + l) * 64 + kk * 32 + quad * 8];
#pragma unroll
      for (int mt = 0; mt < 4; ++mt)
#pragma unroll
        for (int nt = 0; nt < 2; ++nt)
          acc[mt][nt] = MFMA16(af[mt], bf[nt], acc[mt][nt]);
    }
  }

  const int part = c0 / 768;    // block cols never straddle a part (64 | 768)
  const int cbase = c0 % 768;
#pragma unroll
  for (int mt = 0; mt < 4; ++mt) {
#pragma unroll
    for (int nt = 0; nt < 2; ++nt) {
      const int cc = cbase + wn * 32 + nt * 16 + l;  // 0..767
      const int h = cc >> 6, d = cc & 63;
#pragma unroll
      for (int i = 0; i < 4; ++i) {
        const int rg = r0 + wm * 64 + mt * 16 + quad * 4 + i;
        const int b_ = rg >> 10, n = rg & 1023;
        const size_t off = ((size_t)(b_ * 12 + h) * 1024 + n) * 64 + d;
        const float val = acc[mt][nt][i];
        if (part == 0)      qb[off] = (__bf16)(val * QSCALE);
        else if (part == 1) kb[off] = (__bf16)val;
        else                v[off]  = val;
      }
    }
  }
}

// --- 3. fused stats — byte-for-byte the R4/R15 kernel ----------------------
// grid (48, 16), 512 threads (8 waves). Block = (bh, 64 rows) x 1024 cols.
// Chunk = 128 K-rows; wave w owns cols s*128 + w*16 + l. Per wave per chunk:
// 2 global dwordx4 (depth-1 prefetch), 8 MFMA batched, then 16 exp2 batched.
__global__ __launch_bounds__(512) void ks_fused(
    const __bf16* __restrict__ qb, const __bf16* __restrict__ kb,
    float* __restrict__ lse, float* __restrict__ colSP)
{
  __shared__ float sS[1024];
  __shared__ float sP[1024];
  __shared__ float zrow[64];
  const int tid = threadIdx.x;
  const int w = tid >> 6, lane = tid & 63, quad = lane >> 4, l = lane & 15;
  const int bh = blockIdx.x, r0 = blockIdx.y * 64;
  for (int i = tid; i < 1024; i += 512) { sS[i] = 0.f; sP[i] = 0.f; }
  if (tid < 64) zrow[tid] = 0.f;
  __syncthreads();  // init visible

  // Q fragments (pre-scaled): rows r0 + rt*16 + l, dims quad*8 (+0 / +32)
  const __bf16* qbase = qb + ((size_t)bh * 1024 + r0 + l) * 64;
  bf16x8 aq0[4], aq1[4];
#pragma unroll
  for (int rt = 0; rt < 4; ++rt) {
    aq0[rt] = *(const bf16x8*)(qbase + rt * 1024 + quad * 8);
    aq1[rt] = *(const bf16x8*)(qbase + rt * 1024 + 32 + quad * 8);
  }
  // K fragment base: row (w*16 + l), dim quad*8; chunk s adds s*128*64 elems.
  const __bf16* kfrag = kb + (size_t)bh * 65536 + (size_t)(w * 16 + l) * 64 + quad * 8;
  const f32x4 zero = {0.f, 0.f, 0.f, 0.f};

  bf16x8 kf0 = *(const bf16x8*)(kfrag);
  bf16x8 kf1 = *(const bf16x8*)(kfrag + 32);

  float z[16] = {};
  // ---- pass 1: row sums of exp2(score) ----
  for (int s = 0; s < 8; ++s) {
    const bf16x8 c0 = kf0, c1 = kf1;
    const int nxt = (s + 1) & 7;  // s==7 prefetches chunk 0 for pass 2
    kf0 = *(const bf16x8*)(kfrag + (size_t)nxt * 8192);
    kf1 = *(const bf16x8*)(kfrag + (size_t)nxt * 8192 + 32);
    f32x4 av[4];
#pragma unroll
    for (int rt = 0; rt < 4; ++rt) {
      av[rt] = MFMA16(aq0[rt], c0, zero);
      av[rt] = MFMA16(aq1[rt], c1, av[rt]);
    }
#pragma unroll
    for (int rt = 0; rt < 4; ++rt)
#pragma unroll
      for (int r = 0; r < 4; ++r) z[rt * 4 + r] += exp2f(av[rt][r]);
  }
#pragma unroll
  for (int off = 1; off < 16; off <<= 1) {
#pragma unroll
    for (int i = 0; i < 16; ++i) z[i] += __shfl_xor(z[i], off);
  }
  if (l == 0) {
#pragma unroll
    for (int rt = 0; rt < 4; ++rt)
#pragma unroll
      for (int r = 0; r < 4; ++r)
        atomicAdd(&zrow[rt * 16 + quad * 4 + r], z[rt * 4 + r]);
  }
  __syncthreads();  // zrow complete
  if (tid < 64) lse[bh * 1024 + r0 + tid] = __log2f(zrow[tid]);
  float nlb[16];  // -log2(Z)
#pragma unroll
  for (int rt = 0; rt < 4; ++rt)
#pragma unroll
    for (int r = 0; r < 4; ++r)
      nlb[rt * 4 + r] = -__log2f(zrow[rt * 16 + quad * 4 + r]);

  // ---- pass 2: column sums of p and p*log2p ----
  // d = score + (-log2 Z); p = exp2(d); cs += p; cp += p*d. 4 VALU/element.
  for (int s = 0; s < 8; ++s) {
    const bf16x8 c0 = kf0, c1 = kf1;
    if (s < 7) {
      kf0 = *(const bf16x8*)(kfrag + (size_t)(s + 1) * 8192);
      kf1 = *(const bf16x8*)(kfrag + (size_t)(s + 1) * 8192 + 32);
    }
    f32x4 av[4];
#pragma unroll
    for (int rt = 0; rt < 4; ++rt) {
      av[rt] = MFMA16(aq0[rt], c0, zero);
      av[rt] = MFMA16(aq1[rt], c1, av[rt]);
    }
    float cs = 0.f, cp = 0.f;
#pragma unroll
    for (int rt = 0; rt < 4; ++rt) {
#pragma unroll
      for (int r = 0; r < 4; ++r) {
        const float d = av[rt][r] + nlb[rt * 4 + r];
        const float t = exp2f(d);
        cs += t;
        cp = fmaf(t, d, cp);
      }
    }
    cs += __shfl_xor(cs, 16); cs += __shfl_xor(cs, 32);
    cp += __shfl_xor(cp, 16); cp += __shfl_xor(cp, 32);
    if (lane < 16) {  // wave-private columns: plain LDS accumulate
      sS[s * 128 + w * 16 + l] += cs;
      sP[s * 128 + w * 16 + l] += cp;
    }
  }
  __syncthreads();
  for (int i = tid; i < 1024; i += 512) {
    atomicAdd(&colSP[i], sS[i]);
    atomicAdd(&colSP[1024 + i], sP[i]);
  }
}

// --- 5. masked AV -> ctxb. Mask recomputed locally; early-out first. -------
__global__ __launch_bounds__(256) void k_av(
    const __bf16* __restrict__ qb, const __bf16* __restrict__ kb,
    const float* __restrict__ v, const float* __restrict__ lse,
    const float* __restrict__ colSP, const int* __restrict__ cur_epoch,
    __bf16* __restrict__ ctxb)
{
  const int tid = threadIdx.x;
  const int bh = blockIdx.x, r0 = blockIdx.y * 32;
  const int b_ = bh / 12, h = bh % 12;
  __shared__ float qs[32][64];
  __shared__ float pbuf[4][8][64];
  __shared__ float maskS[1024];
  __shared__ int anyKeep;
  if (tid == 0) anyKeep = 0;
  __syncthreads();
  // mask prologue: thr from cur_epoch; entropy per column from colSP (L2-hot)
  {
    const int ce = cur_epoch[0];
    float factor = 0.f;
    for (int i = 1; i <= ce; ++i) factor += __expf(-(float)i);
    factor *= 5.0f;
    const float thr = __logf(768.0f) - factor;
    for (int j = tid; j < 1024; j += 256) {
      const float s = colSP[j];
      const float ent = __logf(s) - (colSP[1024 + j] * LN2) / s;
      const int keep = (ent <= thr) ? 1 : 0;
      maskS[j] = keep ? 1.0f : 0.0f;
      if (keep) anyKeep = 1;  // benign race: all writers store 1
    }
  }
  __syncthreads();
  if (anyKeep == 0) return;  // uniform; ctxb unused downstream in this case
  for (int i = tid; i < 2048; i += 256)
    qs[i >> 6][i & 63] = (float)qb[((size_t)bh * 1024 + r0) * 64 + i];
  __syncthreads();
  const int w = tid >> 6, l = tid & 63, rb = w * 8;
  float ls[8];
#pragma unroll
  for (int i = 0; i < 8; ++i) ls[i] = lse[bh * 1024 + r0 + rb + i];
  float acc[8] = {};
  for (int chunk = 0; chunk < 16; ++chunk) {
    const float mk = maskS[chunk * 64 + l];
    if (__ballot(mk != 0.0f) == 0ull) continue;  // block-uniform
    const __bf16* kp = kb + ((size_t)bh * 1024 + chunk * 64 + l) * 64;
    float s[8] = {};
    for (int d0 = 0; d0 < 64; d0 += 8) {
      const bf16x8 kf = *(const bf16x8*)(kp + d0);
#pragma unroll
      for (int dd = 0; dd < 8; ++dd) {
        const float kv = (float)kf[dd];
#pragma unroll
        for (int i = 0; i < 8; ++i) s[i] += qs[rb + i][d0 + dd] * kv;
      }
    }
    __syncthreads();
#pragma unroll
    for (int i = 0; i < 8; ++i)
      pbuf[w][i][l] = EXP2(s[i] - ls[i]) * mk;
    __syncthreads();
    const float* vp = v + ((size_t)bh * 1024 + chunk * 64) * 64 + l;
    for (int jj = 0; jj < 64; ++jj) {
      const float vv = vp[(size_t)jj * 64];
#pragma unroll
      for (int i = 0; i < 8; ++i) acc[i] += pbuf[w][i][jj] * vv;
    }
  }
#pragma unroll
  for (int i = 0; i < 8; ++i)
    ctxb[((size_t)(b_ * 1024 + r0 + rb + i)) * 768 + h * 64 + l] = (__bf16)acc[i];
}

// --- 6. proj GEMM: out = ctxb @ pwb.T + bias; keep-any recomputed. ---------
__global__ __launch_bounds__(256) void kg_proj(
    const __bf16* __restrict__ A, const __bf16* __restrict__ Bm,
    const float* __restrict__ bias, const float* __restrict__ colSP,
    const int* __restrict__ cur_epoch, float* __restrict__ out)
{
  const int tid = threadIdx.x;
  const int w = tid >> 6, lane = tid & 63, quad = lane >> 4, l = lane & 15;
  const int r0 = blockIdx.y * 64, c0 = blockIdx.x * 64;
  __shared__ int anyKeep;
  if (tid == 0) anyKeep = 0;
  __syncthreads();
  {
    const int ce = cur_epoch[0];
    float factor = 0.f;
    for (int i = 1; i <= ce; ++i) factor += __expf(-(float)i);
    factor *= 5.0f;
    const float thr = __logf(768.0f) - factor;
    for (int j = tid; j < 1024; j += 256) {
      const float s = colSP[j];
      const float ent = __logf(s) - (colSP[1024 + j] * LN2) / s;
      if (ent <= thr) anyKeep = 1;  // benign race
    }
  }
  __syncthreads();
  if (anyKeep == 0) {  // ctx == 0 -> out = bias (uniform branch)
#pragma unroll
    for (int ct = 0; ct < 4; ++ct) {
      const int c = c0 + ct * 16 + l;
      const float bv = bias[c];
#pragma unroll
      for (int i = 0; i < 4; ++i) {
        const int rg = r0 + w * 16 + quad * 4 + i;
        out[(size_t)rg * 768 + c] = bv;
      }
    }
    return;
  }
  __shared__ __bf16 As[64 * 72];
  __shared__ __bf16 Bs[64 * 72];
  const int row = tid >> 3, ko = (tid & 7) * 8;
  const f32x4 zero = {0.f, 0.f, 0.f, 0.f};
  f32x4 acc[4];
#pragma unroll
  for (int ct = 0; ct < 4; ++ct) acc[ct] = zero;

  uint4 a0 = *(const uint4*)(A + (size_t)(r0 + row) * 768 + ko);
  uint4 a1 = *(const uint4*)(A + (size_t)(r0 + row + 32) * 768 + ko);
  uint4 b0 = *(const uint4*)(Bm + (size_t)(c0 + row) * 768 + ko);
  uint4 b1 = *(const uint4*)(Bm + (size_t)(c0 + row + 32) * 768 + ko);

  for (int k0 = 0; k0 < 768; k0 += 64) {
    __syncthreads();
    *(uint4*)&As[row * 72 + ko] = a0;
    *(uint4*)&As[(row + 32) * 72 + ko] = a1;
    *(uint4*)&Bs[row * 72 + ko] = b0;
    *(uint4*)&Bs[(row + 32) * 72 + ko] = b1;
    __syncthreads();
    if (k0 < 704) {
      a0 = *(const uint4*)(A + (size_t)(r0 + row) * 768 + k0 + 64 + ko);
      a1 = *(const uint4*)(A + (size_t)(r0 + row + 32) * 768 + k0 + 64 + ko);
      b0 = *(const uint4*)(Bm + (size_t)(c0 + row) * 768 + k0 + 64 + ko);
      b1 = *(const uint4*)(Bm + (size_t)(c0 + row + 32) * 768 + k0 + 64 + ko);
    }
    const bf16x8 af0 = *(const bf16x8*)&As[(w * 16 + l) * 72 + quad * 8];
    const bf16x8 af1 = *(const bf16x8*)&As[(w * 16 + l) * 72 + 32 + quad * 8];
#pragma unroll
    for (int ct = 0; ct < 4; ++ct) {
      const bf16x8 bf0 = *(const bf16x8*)&Bs[(ct * 16 + l) * 72 + quad * 8];
      const bf16x8 bf1 = *(const bf16x8*)&Bs[(ct * 16 + l) * 72 + 32 + quad * 8];
      acc[ct] = MFMA16(af0, bf0, acc[ct]);
      acc[ct] = MFMA16(af1, bf1, acc[ct]);
    }
  }
#pragma unroll
  for (int ct = 0; ct < 4; ++ct) {
    const int c = c0 + ct * 16 + l;
#pragma unroll
    for (int i = 0; i < 4; ++i) {
      const int rg = r0 + w * 16 + quad * 4 + i;
      out[(size_t)rg * 768 + c] = acc[ct][i] + bias[c];
    }
  }
}

extern "C" void kernel_launch(void* const* d_in, const int* in_sizes, int n_in,
                              void* d_out, int out_size, void* d_ws, size_t ws_size,
                              hipStream_t stream)
{
  const float* x      = (const float*)d_in[0];
  const float* qkv_w  = (const float*)d_in[1];
  const float* proj_w = (const float*)d_in[2];
  const float* proj_b = (const float*)d_in[3];
  const int*   cur_ep = (const int*)d_in[4];

  char* W = (char*)d_ws;
  __bf16* xb    = (__bf16*)(W + 0);
  __bf16* qwb   = (__bf16*)(W + 6291456);
  __bf16* pwb   = (__bf16*)(W + 9830400);
  __bf16* qb    = (__bf16*)(W + 11010048);
  __bf16* kb    = (__bf16*)(W + 17301504);
  float*  v     = (float*) (W + 23592960);
  __bf16* ctxb  = (__bf16*)(W + 36175872);
  float*  lse   = (float*) (W + 42467328);
  float*  colSP = (float*) (W + 42668544);
  float*  out   = (float*)d_out;

  kc_conv<<<5376, 256, 0, stream>>>(x, qkv_w, proj_w, xb, qwb, pwb, colSP);
  kg_qkv<<<dim3(36, 32), 256, 0, stream>>>(xb, qwb, qb, kb, v);
  ks_fused<<<dim3(48, 16), 512, 0, stream>>>(qb, kb, lse, colSP);
  k_av<<<dim3(48, 32), 256, 0, stream>>>(qb, kb, v, lse, colSP, cur_ep, ctxb);
  kg_proj<<<dim3(12, 64), 256, 0, stream>>>(ctxb, pwb, proj_b, colSP, cur_ep, out);
}

// Round 11
// 157.736 us; speedup vs baseline: 1.5006x; 1.0071x over previous
//
#include <hip/hip_runtime.h>

// ---------------------------------------------------------------------------
// EntropyPrunedSelfAttention  (B=4, N=1024, C=768, H=12, hd=64)
// Round 22: single-variable experiment — ks_fused chunk loops get
// #pragma unroll 2 (cross-chunk scheduler visibility: interleave chunk s's
// exp2 chain with chunk s+1's MFMAs). Everything else byte-identical to R10
// (kg_qkv 128x64 retile, mask recomputed in k_av/kg_proj prologues).
// R10 post-mortem: clean container confirmed ks_fused 47.7us / total 158.9;
// R9's 66us was clock noise. Totals flat 157.8-161 since R0.
//
// Workspace (byte offsets):
//   xb      bf16[4096*768]      @ 0
//   qwb     bf16[2304*768]      @ 6291456
//   pwb     bf16[768*768]       @ 9830400
//   qb      bf16[48*1024*64]    @ 11010048   (pre-scaled by 0.125*log2e)
//   kb      bf16[48*1024*64]    @ 17301504
//   v       f32 [48*1024*64]    @ 23592960
//   ctxb    bf16[4096*768]      @ 36175872
//   lse     f32 [48*1024]       @ 42467328   (log2 of row-sum Z)
//   colSP   f32 [2048]          @ 42668544   (colS[1024] ++ colP_log2[1024])
// total ~42.7 MB
// ---------------------------------------------------------------------------

typedef __bf16 bf16x8 __attribute__((ext_vector_type(8)));
typedef __bf16 bf16x4 __attribute__((ext_vector_type(4)));
typedef float  f32x4  __attribute__((ext_vector_type(4)));

#define MFMA16(a, b, c) __builtin_amdgcn_mfma_f32_16x16x32_bf16((a), (b), (c), 0, 0, 0)
#define QSCALE 0.18033688f   /* 0.125 * log2(e) */
#define LN2    0.69314718f

#if __has_builtin(__builtin_amdgcn_exp2f)
#define EXP2(x) __builtin_amdgcn_exp2f(x)
#else
#define EXP2(x) exp2f(x)
#endif

__device__ __forceinline__ void ld_glds16(const __bf16* g, __bf16* s) {
  __builtin_amdgcn_global_load_lds(
      (const __attribute__((address_space(1))) unsigned int*)g,
      (__attribute__((address_space(3))) unsigned int*)s, 16, 0, 0);
}

// --- 1. fp32 -> bf16 conversion + zero colSP -------------------------------
__global__ __launch_bounds__(256) void kc_conv(
    const float* __restrict__ x, const float* __restrict__ qw, const float* __restrict__ pw,
    __bf16* __restrict__ xb, __bf16* __restrict__ qwb, __bf16* __restrict__ pwb,
    float* __restrict__ colSP)
{
  const int i = blockIdx.x * 256 + threadIdx.x;
  const float4* src;
  __bf16* dst;
  int j;
  if (i < 786432)       { src = (const float4*)x;  dst = xb;  j = i; }
  else if (i < 1228800) { src = (const float4*)qw; dst = qwb; j = i - 786432; }
  else                  { src = (const float4*)pw; dst = pwb; j = i - 1228800; }
  const float4 f = src[j];
  bf16x4 o;
  o[0] = (__bf16)f.x; o[1] = (__bf16)f.y; o[2] = (__bf16)f.z; o[3] = (__bf16)f.w;
  *(bf16x4*)(dst + 4 * (size_t)j) = o;
  if (i < 2048) colSP[i] = 0.f;
}

// --- 2. QKV GEMM: 128x64 tile, grid (36,32) = 1152 blocks = 4.5/CU ---------
__global__ __launch_bounds__(256) void kg_qkv(
    const __bf16* __restrict__ A, const __bf16* __restrict__ Bm,
    __bf16* __restrict__ qb, __bf16* __restrict__ kb, float* __restrict__ v)
{
  __shared__ __bf16 As[128 * 64];   // 16 KB
  __shared__ __bf16 Bs[64 * 64];    // 8 KB
  const int tid = threadIdx.x;
  const int w = tid >> 6, lane = tid & 63, quad = lane >> 4, l = lane & 15;
  const int wm = w >> 1, wn = w & 1;
  const int r0 = blockIdx.y * 128, c0 = blockIdx.x * 64;
  const int srow = lane >> 3, skk = (lane & 7) * 8;

  f32x4 acc[4][2] = {};

  for (int k0 = 0; k0 < 768; k0 += 64) {
    if (k0) __syncthreads();  // previous compute done -> LDS writable
#pragma unroll
    for (int s = 0; s < 4; ++s) {
      const int si = w * 4 + s;               // 0..15 -> A rows 0..127
      ld_glds16(A + (size_t)(r0 + si * 8 + srow) * 768 + k0 + skk, &As[si * 512]);
    }
#pragma unroll
    for (int s = 0; s < 2; ++s) {
      const int sj = w * 2 + s;               // 0..7  -> B rows 0..63
      ld_glds16(Bm + (size_t)(c0 + sj * 8 + srow) * 768 + k0 + skk, &Bs[sj * 512]);
    }
    __syncthreads();  // drains vmcnt -> staged tiles visible
#pragma unroll
    for (int kk = 0; kk < 2; ++kk) {
      bf16x8 af[4], bf[2];
#pragma unroll
      for (int t = 0; t < 4; ++t)
        af[t] = *(const bf16x8*)&As[(wm * 64 + t * 16 + l) * 64 + kk * 32 + quad * 8];
#pragma unroll
      for (int t = 0; t < 2; ++t)
        bf[t] = *(const bf16x8*)&Bs[(wn * 32 + t * 16 + l) * 64 + kk * 32 + quad * 8];
#pragma unroll
      for (int mt = 0; mt < 4; ++mt)
#pragma unroll
        for (int nt = 0; nt < 2; ++nt)
          acc[mt][nt] = MFMA16(af[mt], bf[nt], acc[mt][nt]);
    }
  }

  const int part = c0 / 768;    // block cols never straddle a part (64 | 768)
  const int cbase = c0 % 768;
#pragma unroll
  for (int mt = 0; mt < 4; ++mt) {
#pragma unroll
    for (int nt = 0; nt < 2; ++nt) {
      const int cc = cbase + wn * 32 + nt * 16 + l;  // 0..767
      const int h = cc >> 6, d = cc & 63;
#pragma unroll
      for (int i = 0; i < 4; ++i) {
        const int rg = r0 + wm * 64 + mt * 16 + quad * 4 + i;
        const int b_ = rg >> 10, n = rg & 1023;
        const size_t off = ((size_t)(b_ * 12 + h) * 1024 + n) * 64 + d;
        const float val = acc[mt][nt][i];
        if (part == 0)      qb[off] = (__bf16)(val * QSCALE);
        else if (part == 1) kb[off] = (__bf16)val;
        else                v[off]  = val;
      }
    }
  }
}

// --- 3. fused stats — R4 structure + #pragma unroll 2 on chunk loops -------
// grid (48, 16), 512 threads (8 waves). Block = (bh, 64 rows) x 1024 cols.
// Chunk = 128 K-rows; wave w owns cols s*128 + w*16 + l. Per wave per chunk:
// 2 global dwordx4 (depth-1 prefetch), 8 MFMA batched, then 16 exp2 batched.
__global__ __launch_bounds__(512) void ks_fused(
    const __bf16* __restrict__ qb, const __bf16* __restrict__ kb,
    float* __restrict__ lse, float* __restrict__ colSP)
{
  __shared__ float sS[1024];
  __shared__ float sP[1024];
  __shared__ float zrow[64];
  const int tid = threadIdx.x;
  const int w = tid >> 6, lane = tid & 63, quad = lane >> 4, l = lane & 15;
  const int bh = blockIdx.x, r0 = blockIdx.y * 64;
  for (int i = tid; i < 1024; i += 512) { sS[i] = 0.f; sP[i] = 0.f; }
  if (tid < 64) zrow[tid] = 0.f;
  __syncthreads();  // init visible

  // Q fragments (pre-scaled): rows r0 + rt*16 + l, dims quad*8 (+0 / +32)
  const __bf16* qbase = qb + ((size_t)bh * 1024 + r0 + l) * 64;
  bf16x8 aq0[4], aq1[4];
#pragma unroll
  for (int rt = 0; rt < 4; ++rt) {
    aq0[rt] = *(const bf16x8*)(qbase + rt * 1024 + quad * 8);
    aq1[rt] = *(const bf16x8*)(qbase + rt * 1024 + 32 + quad * 8);
  }
  // K fragment base: row (w*16 + l), dim quad*8; chunk s adds s*128*64 elems.
  const __bf16* kfrag = kb + (size_t)bh * 65536 + (size_t)(w * 16 + l) * 64 + quad * 8;
  const f32x4 zero = {0.f, 0.f, 0.f, 0.f};

  bf16x8 kf0 = *(const bf16x8*)(kfrag);
  bf16x8 kf1 = *(const bf16x8*)(kfrag + 32);

  float z[16] = {};
  // ---- pass 1: row sums of exp2(score) ----
#pragma unroll 2
  for (int s = 0; s < 8; ++s) {
    const bf16x8 c0 = kf0, c1 = kf1;
    const int nxt = (s + 1) & 7;  // s==7 prefetches chunk 0 for pass 2
    kf0 = *(const bf16x8*)(kfrag + (size_t)nxt * 8192);
    kf1 = *(const bf16x8*)(kfrag + (size_t)nxt * 8192 + 32);
    f32x4 av[4];
#pragma unroll
    for (int rt = 0; rt < 4; ++rt) {
      av[rt] = MFMA16(aq0[rt], c0, zero);
      av[rt] = MFMA16(aq1[rt], c1, av[rt]);
    }
#pragma unroll
    for (int rt = 0; rt < 4; ++rt)
#pragma unroll
      for (int r = 0; r < 4; ++r) z[rt * 4 + r] += exp2f(av[rt][r]);
  }
#pragma unroll
  for (int off = 1; off < 16; off <<= 1) {
#pragma unroll
    for (int i = 0; i < 16; ++i) z[i] += __shfl_xor(z[i], off);
  }
  if (l == 0) {
#pragma unroll
    for (int rt = 0; rt < 4; ++rt)
#pragma unroll
      for (int r = 0; r < 4; ++r)
        atomicAdd(&zrow[rt * 16 + quad * 4 + r], z[rt * 4 + r]);
  }
  __syncthreads();  // zrow complete
  if (tid < 64) lse[bh * 1024 + r0 + tid] = __log2f(zrow[tid]);
  float nlb[16];  // -log2(Z)
#pragma unroll
  for (int rt = 0; rt < 4; ++rt)
#pragma unroll
    for (int r = 0; r < 4; ++r)
      nlb[rt * 4 + r] = -__log2f(zrow[rt * 16 + quad * 4 + r]);

  // ---- pass 2: column sums of p and p*log2p ----
  // d = score + (-log2 Z); p = exp2(d); cs += p; cp += p*d. 4 VALU/element.
#pragma unroll 2
  for (int s = 0; s < 8; ++s) {
    const bf16x8 c0 = kf0, c1 = kf1;
    if (s < 7) {
      kf0 = *(const bf16x8*)(kfrag + (size_t)(s + 1) * 8192);
      kf1 = *(const bf16x8*)(kfrag + (size_t)(s + 1) * 8192 + 32);
    }
    f32x4 av[4];
#pragma unroll
    for (int rt = 0; rt < 4; ++rt) {
      av[rt] = MFMA16(aq0[rt], c0, zero);
      av[rt] = MFMA16(aq1[rt], c1, av[rt]);
    }
    float cs = 0.f, cp = 0.f;
#pragma unroll
    for (int rt = 0; rt < 4; ++rt) {
#pragma unroll
      for (int r = 0; r < 4; ++r) {
        const float d = av[rt][r] + nlb[rt * 4 + r];
        const float t = exp2f(d);
        cs += t;
        cp = fmaf(t, d, cp);
      }
    }
    cs += __shfl_xor(cs, 16); cs += __shfl_xor(cs, 32);
    cp += __shfl_xor(cp, 16); cp += __shfl_xor(cp, 32);
    if (lane < 16) {  // wave-private columns: plain LDS accumulate
      sS[s * 128 + w * 16 + l] += cs;
      sP[s * 128 + w * 16 + l] += cp;
    }
  }
  __syncthreads();
  for (int i = tid; i < 1024; i += 512) {
    atomicAdd(&colSP[i], sS[i]);
    atomicAdd(&colSP[1024 + i], sP[i]);
  }
}

// --- 5. masked AV -> ctxb. Mask recomputed locally; early-out first. -------
__global__ __launch_bounds__(256) void k_av(
    const __bf16* __restrict__ qb, const __bf16* __restrict__ kb,
    const float* __restrict__ v, const float* __restrict__ lse,
    const float* __restrict__ colSP, const int* __restrict__ cur_epoch,
    __bf16* __restrict__ ctxb)
{
  const int tid = threadIdx.x;
  const int bh = blockIdx.x, r0 = blockIdx.y * 32;
  const int b_ = bh / 12, h = bh % 12;
  __shared__ float qs[32][64];
  __shared__ float pbuf[4][8][64];
  __shared__ float maskS[1024];
  __shared__ int anyKeep;
  if (tid == 0) anyKeep = 0;
  __syncthreads();
  // mask prologue: thr from cur_epoch; entropy per column from colSP (L2-hot)
  {
    const int ce = cur_epoch[0];
    float factor = 0.f;
    for (int i = 1; i <= ce; ++i) factor += __expf(-(float)i);
    factor *= 5.0f;
    const float thr = __logf(768.0f) - factor;
    for (int j = tid; j < 1024; j += 256) {
      const float s = colSP[j];
      const float ent = __logf(s) - (colSP[1024 + j] * LN2) / s;
      const int keep = (ent <= thr) ? 1 : 0;
      maskS[j] = keep ? 1.0f : 0.0f;
      if (keep) anyKeep = 1;  // benign race: all writers store 1
    }
  }
  __syncthreads();
  if (anyKeep == 0) return;  // uniform; ctxb unused downstream in this case
  for (int i = tid; i < 2048; i += 256)
    qs[i >> 6][i & 63] = (float)qb[((size_t)bh * 1024 + r0) * 64 + i];
  __syncthreads();
  const int w = tid >> 6, l = tid & 63, rb = w * 8;
  float ls[8];
#pragma unroll
  for (int i = 0; i < 8; ++i) ls[i] = lse[bh * 1024 + r0 + rb + i];
  float acc[8] = {};
  for (int chunk = 0; chunk < 16; ++chunk) {
    const float mk = maskS[chunk * 64 + l];
    if (__ballot(mk != 0.0f) == 0ull) continue;  // block-uniform
    const __bf16* kp = kb + ((size_t)bh * 1024 + chunk * 64 + l) * 64;
    float s[8] = {};
    for (int d0 = 0; d0 < 64; d0 += 8) {
      const bf16x8 kf = *(const bf16x8*)(kp + d0);
#pragma unroll
      for (int dd = 0; dd < 8; ++dd) {
        const float kv = (float)kf[dd];
#pragma unroll
        for (int i = 0; i < 8; ++i) s[i] += qs[rb + i][d0 + dd] * kv;
      }
    }
    __syncthreads();
#pragma unroll
    for (int i = 0; i < 8; ++i)
      pbuf[w][i][l] = EXP2(s[i] - ls[i]) * mk;
    __syncthreads();
    const float* vp = v + ((size_t)bh * 1024 + chunk * 64) * 64 + l;
    for (int jj = 0; jj < 64; ++jj) {
      const float vv = vp[(size_t)jj * 64];
#pragma unroll
      for (int i = 0; i < 8; ++i) acc[i] += pbuf[w][i][jj] * vv;
    }
  }
#pragma unroll
  for (int i = 0; i < 8; ++i)
    ctxb[((size_t)(b_ * 1024 + r0 + rb + i)) * 768 + h * 64 + l] = (__bf16)acc[i];
}

// --- 6. proj GEMM: out = ctxb @ pwb.T + bias; keep-any recomputed. ---------
__global__ __launch_bounds__(256) void kg_proj(
    const __bf16* __restrict__ A, const __bf16* __restrict__ Bm,
    const float* __restrict__ bias, const float* __restrict__ colSP,
    const int* __restrict__ cur_epoch, float* __restrict__ out)
{
  const int tid = threadIdx.x;
  const int w = tid >> 6, lane = tid & 63, quad = lane >> 4, l = lane & 15;
  const int r0 = blockIdx.y * 64, c0 = blockIdx.x * 64;
  __shared__ int anyKeep;
  if (tid == 0) anyKeep = 0;
  __syncthreads();
  {
    const int ce = cur_epoch[0];
    float factor = 0.f;
    for (int i = 1; i <= ce; ++i) factor += __expf(-(float)i);
    factor *= 5.0f;
    const float thr = __logf(768.0f) - factor;
    for (int j = tid; j < 1024; j += 256) {
      const float s = colSP[j];
      const float ent = __logf(s) - (colSP[1024 + j] * LN2) / s;
      if (ent <= thr) anyKeep = 1;  // benign race
    }
  }
  __syncthreads();
  if (anyKeep == 0) {  // ctx == 0 -> out = bias (uniform branch)
#pragma unroll
    for (int ct = 0; ct < 4; ++ct) {
      const int c = c0 + ct * 16 + l;
      const float bv = bias[c];
#pragma unroll
      for (int i = 0; i < 4; ++i) {
        const int rg = r0 + w * 16 + quad * 4 + i;
        out[(size_t)rg * 768 + c] = bv;
      }
    }
    return;
  }
  __shared__ __bf16 As[64 * 72];
  __shared__ __bf16 Bs[64 * 72];
  const int row = tid >> 3, ko = (tid & 7) * 8;
  const f32x4 zero = {0.f, 0.f, 0.f, 0.f};
  f32x4 acc[4];
#pragma unroll
  for (int ct = 0; ct < 4; ++ct) acc[ct] = zero;

  uint4 a0 = *(const uint4*)(A + (size_t)(r0 + row) * 768 + ko);
  uint4 a1 = *(const uint4*)(A + (size_t)(r0 + row + 32) * 768 + ko);
  uint4 b0 = *(const uint4*)(Bm + (size_t)(c0 + row) * 768 + ko);
  uint4 b1 = *(const uint4*)(Bm + (size_t)(c0 + row + 32) * 768 + ko);

  for (int k0 = 0; k0 < 768; k0 += 64) {
    __syncthreads();
    *(uint4*)&As[row * 72 + ko] = a0;
    *(uint4*)&As[(row + 32) * 72 + ko] = a1;
    *(uint4*)&Bs[row * 72 + ko] = b0;
    *(uint4*)&Bs[(row + 32) * 72 + ko] = b1;
    __syncthreads();
    if (k0 < 704) {
      a0 = *(const uint4*)(A + (size_t)(r0 + row) * 768 + k0 + 64 + ko);
      a1 = *(const uint4*)(A + (size_t)(r0 + row + 32) * 768 + k0 + 64 + ko);
      b0 = *(const uint4*)(Bm + (size_t)(c0 + row) * 768 + k0 + 64 + ko);
      b1 = *(const uint4*)(Bm + (size_t)(c0 + row + 32) * 768 + k0 + 64 + ko);
    }
    const bf16x8 af0 = *(const bf16x8*)&As[(w * 16 + l) * 72 + quad * 8];
    const bf16x8 af1 = *(const bf16x8*)&As[(w * 16 + l) * 72 + 32 + quad * 8];
#pragma unroll
    for (int ct = 0; ct < 4; ++ct) {
      const bf16x8 bf0 = *(const bf16x8*)&Bs[(ct * 16 + l) * 72 + quad * 8];
      const bf16x8 bf1 = *(const bf16x8*)&Bs[(ct * 16 + l) * 72 + 32 + quad * 8];
      acc[ct] = MFMA16(af0, bf0, acc[ct]);
      acc[ct] = MFMA16(af1, bf1, acc[ct]);
    }
  }
#pragma unroll
  for (int ct = 0; ct < 4; ++ct) {
    const int c = c0 + ct * 16 + l;
#pragma unroll
    for (int i = 0; i < 4; ++i) {
      const int rg = r0 + w * 16 + quad * 4 + i;
      out[(size_t)rg * 768 + c] = acc[ct][i] + bias[c];
    }
  }
}

extern "C" void kernel_launch(void* const* d_in, const int* in_sizes, int n_in,
                              void* d_out, int out_size, void* d_ws, size_t ws_size,
                              hipStream_t stream)
{
  const float* x      = (const float*)d_in[0];
  const float* qkv_w  = (const float*)d_in[1];
  const float* proj_w = (const float*)d_in[2];
  const float* proj_b = (const float*)d_in[3];
  const int*   cur_ep = (const int*)d_in[4];

  char* W = (char*)d_ws;
  __bf16* xb    = (__bf16*)(W + 0);
  __bf16* qwb   = (__bf16*)(W + 6291456);
  __bf16* pwb   = (__bf16*)(W + 9830400);
  __bf16* qb    = (__bf16*)(W + 11010048);
  __bf16* kb    = (__bf16*)(W + 17301504);
  float*  v     = (float*) (W + 23592960);
  __bf16* ctxb  = (__bf16*)(W + 36175872);
  float*  lse   = (float*) (W + 42467328);
  float*  colSP = (float*) (W + 42668544);
  float*  out   = (float*)d_out;

  kc_conv<<<5376, 256, 0, stream>>>(x, qkv_w, proj_w, xb, qwb, pwb, colSP);
  kg_qkv<<<dim3(36, 32), 256, 0, stream>>>(xb, qwb, qb, kb, v);
  ks_fused<<<dim3(48, 16), 512, 0, stream>>>(qb, kb, lse, colSP);
  k_av<<<dim3(48, 32), 256, 0, stream>>>(qb, kb, v, lse, colSP, cur_ep, ctxb);
  kg_proj<<<dim3(12, 64), 256, 0, stream>>>(ctxb, pwb, proj_b, colSP, cur_ep, out);
}

// Round 12
// 156.402 us; speedup vs baseline: 1.5134x; 1.0085x over previous
//
#include <hip/hip_runtime.h>

// ---------------------------------------------------------------------------
// EntropyPrunedSelfAttention  (B=4, N=1024, C=768, H=12, hd=64)
// Round 23: last evidence-backed polish before plateau declaration.
// (a) ks_fused: exp2f -> __builtin_amdgcn_exp2f (R16 showed libm exp2f costs
//     ~5 VALU ops: VALUBusy halved 52->25% with builtin; args in [-30,10] so
//     bare v_exp_f32 is safe). Unroll-2 reverted (R11: null/slightly worse).
// (b) v stored bf16 (was f32): halves v epilogue write traffic in kg_qkv;
//     AV path reads bf16 (dead path for keep=0 inputs; precision = q/k).
// Everything else byte-identical to R11/R10.
//
// Workspace (byte offsets):
//   xb      bf16[4096*768]      @ 0
//   qwb     bf16[2304*768]      @ 6291456
//   pwb     bf16[768*768]       @ 9830400
//   qb      bf16[48*1024*64]    @ 11010048   (pre-scaled by 0.125*log2e)
//   kb      bf16[48*1024*64]    @ 17301504
//   v       bf16[48*1024*64]    @ 23592960   (now bf16; 6.3MB)
//   ctxb    bf16[4096*768]      @ 36175872
//   lse     f32 [48*1024]       @ 42467328   (log2 of row-sum Z)
//   colSP   f32 [2048]          @ 42668544   (colS[1024] ++ colP_log2[1024])
// total ~42.7 MB
// ---------------------------------------------------------------------------

typedef __bf16 bf16x8 __attribute__((ext_vector_type(8)));
typedef __bf16 bf16x4 __attribute__((ext_vector_type(4)));
typedef float  f32x4  __attribute__((ext_vector_type(4)));

#define MFMA16(a, b, c) __builtin_amdgcn_mfma_f32_16x16x32_bf16((a), (b), (c), 0, 0, 0)
#define QSCALE 0.18033688f   /* 0.125 * log2(e) */
#define LN2    0.69314718f

#if __has_builtin(__builtin_amdgcn_exp2f)
#define EXP2(x) __builtin_amdgcn_exp2f(x)
#else
#define EXP2(x) exp2f(x)
#endif

__device__ __forceinline__ void ld_glds16(const __bf16* g, __bf16* s) {
  __builtin_amdgcn_global_load_lds(
      (const __attribute__((address_space(1))) unsigned int*)g,
      (__attribute__((address_space(3))) unsigned int*)s, 16, 0, 0);
}

// --- 1. fp32 -> bf16 conversion + zero colSP -------------------------------
__global__ __launch_bounds__(256) void kc_conv(
    const float* __restrict__ x, const float* __restrict__ qw, const float* __restrict__ pw,
    __bf16* __restrict__ xb, __bf16* __restrict__ qwb, __bf16* __restrict__ pwb,
    float* __restrict__ colSP)
{
  const int i = blockIdx.x * 256 + threadIdx.x;
  const float4* src;
  __bf16* dst;
  int j;
  if (i < 786432)       { src = (const float4*)x;  dst = xb;  j = i; }
  else if (i < 1228800) { src = (const float4*)qw; dst = qwb; j = i - 786432; }
  else                  { src = (const float4*)pw; dst = pwb; j = i - 1228800; }
  const float4 f = src[j];
  bf16x4 o;
  o[0] = (__bf16)f.x; o[1] = (__bf16)f.y; o[2] = (__bf16)f.z; o[3] = (__bf16)f.w;
  *(bf16x4*)(dst + 4 * (size_t)j) = o;
  if (i < 2048) colSP[i] = 0.f;
}

// --- 2. QKV GEMM: 128x64 tile, grid (36,32) = 1152 blocks = 4.5/CU ---------
__global__ __launch_bounds__(256) void kg_qkv(
    const __bf16* __restrict__ A, const __bf16* __restrict__ Bm,
    __bf16* __restrict__ qb, __bf16* __restrict__ kb, __bf16* __restrict__ v)
{
  __shared__ __bf16 As[128 * 64];   // 16 KB
  __shared__ __bf16 Bs[64 * 64];    // 8 KB
  const int tid = threadIdx.x;
  const int w = tid >> 6, lane = tid & 63, quad = lane >> 4, l = lane & 15;
  const int wm = w >> 1, wn = w & 1;
  const int r0 = blockIdx.y * 128, c0 = blockIdx.x * 64;
  const int srow = lane >> 3, skk = (lane & 7) * 8;

  f32x4 acc[4][2] = {};

  for (int k0 = 0; k0 < 768; k0 += 64) {
    if (k0) __syncthreads();  // previous compute done -> LDS writable
#pragma unroll
    for (int s = 0; s < 4; ++s) {
      const int si = w * 4 + s;               // 0..15 -> A rows 0..127
      ld_glds16(A + (size_t)(r0 + si * 8 + srow) * 768 + k0 + skk, &As[si * 512]);
    }
#pragma unroll
    for (int s = 0; s < 2; ++s) {
      const int sj = w * 2 + s;               // 0..7  -> B rows 0..63
      ld_glds16(Bm + (size_t)(c0 + sj * 8 + srow) * 768 + k0 + skk, &Bs[sj * 512]);
    }
    __syncthreads();  // drains vmcnt -> staged tiles visible
#pragma unroll
    for (int kk = 0; kk < 2; ++kk) {
      bf16x8 af[4], bf[2];
#pragma unroll
      for (int t = 0; t < 4; ++t)
        af[t] = *(const bf16x8*)&As[(wm * 64 + t * 16 + l) * 64 + kk * 32 + quad * 8];
#pragma unroll
      for (int t = 0; t < 2; ++t)
        bf[t] = *(const bf16x8*)&Bs[(wn * 32 + t * 16 + l) * 64 + kk * 32 + quad * 8];
#pragma unroll
      for (int mt = 0; mt < 4; ++mt)
#pragma unroll
        for (int nt = 0; nt < 2; ++nt)
          acc[mt][nt] = MFMA16(af[mt], bf[nt], acc[mt][nt]);
    }
  }

  const int part = c0 / 768;    // block cols never straddle a part (64 | 768)
  const int cbase = c0 % 768;
#pragma unroll
  for (int mt = 0; mt < 4; ++mt) {
#pragma unroll
    for (int nt = 0; nt < 2; ++nt) {
      const int cc = cbase + wn * 32 + nt * 16 + l;  // 0..767
      const int h = cc >> 6, d = cc & 63;
#pragma unroll
      for (int i = 0; i < 4; ++i) {
        const int rg = r0 + wm * 64 + mt * 16 + quad * 4 + i;
        const int b_ = rg >> 10, n = rg & 1023;
        const size_t off = ((size_t)(b_ * 12 + h) * 1024 + n) * 64 + d;
        const float val = acc[mt][nt][i];
        if (part == 0)      qb[off] = (__bf16)(val * QSCALE);
        else if (part == 1) kb[off] = (__bf16)val;
        else                v[off]  = (__bf16)val;
      }
    }
  }
}

// --- 3. fused stats — R4 structure; exp2f -> builtin (single variable) -----
// grid (48, 16), 512 threads (8 waves). Block = (bh, 64 rows) x 1024 cols.
// Chunk = 128 K-rows; wave w owns cols s*128 + w*16 + l. Per wave per chunk:
// 2 global dwordx4 (depth-1 prefetch), 8 MFMA batched, then 16 exp2 batched.
__global__ __launch_bounds__(512) void ks_fused(
    const __bf16* __restrict__ qb, const __bf16* __restrict__ kb,
    float* __restrict__ lse, float* __restrict__ colSP)
{
  __shared__ float sS[1024];
  __shared__ float sP[1024];
  __shared__ float zrow[64];
  const int tid = threadIdx.x;
  const int w = tid >> 6, lane = tid & 63, quad = lane >> 4, l = lane & 15;
  const int bh = blockIdx.x, r0 = blockIdx.y * 64;
  for (int i = tid; i < 1024; i += 512) { sS[i] = 0.f; sP[i] = 0.f; }
  if (tid < 64) zrow[tid] = 0.f;
  __syncthreads();  // init visible

  // Q fragments (pre-scaled): rows r0 + rt*16 + l, dims quad*8 (+0 / +32)
  const __bf16* qbase = qb + ((size_t)bh * 1024 + r0 + l) * 64;
  bf16x8 aq0[4], aq1[4];
#pragma unroll
  for (int rt = 0; rt < 4; ++rt) {
    aq0[rt] = *(const bf16x8*)(qbase + rt * 1024 + quad * 8);
    aq1[rt] = *(const bf16x8*)(qbase + rt * 1024 + 32 + quad * 8);
  }
  // K fragment base: row (w*16 + l), dim quad*8; chunk s adds s*128*64 elems.
  const __bf16* kfrag = kb + (size_t)bh * 65536 + (size_t)(w * 16 + l) * 64 + quad * 8;
  const f32x4 zero = {0.f, 0.f, 0.f, 0.f};

  bf16x8 kf0 = *(const bf16x8*)(kfrag);
  bf16x8 kf1 = *(const bf16x8*)(kfrag + 32);

  float z[16] = {};
  // ---- pass 1: row sums of exp2(score) ----
  for (int s = 0; s < 8; ++s) {
    const bf16x8 c0 = kf0, c1 = kf1;
    const int nxt = (s + 1) & 7;  // s==7 prefetches chunk 0 for pass 2
    kf0 = *(const bf16x8*)(kfrag + (size_t)nxt * 8192);
    kf1 = *(const bf16x8*)(kfrag + (size_t)nxt * 8192 + 32);
    f32x4 av[4];
#pragma unroll
    for (int rt = 0; rt < 4; ++rt) {
      av[rt] = MFMA16(aq0[rt], c0, zero);
      av[rt] = MFMA16(aq1[rt], c1, av[rt]);
    }
#pragma unroll
    for (int rt = 0; rt < 4; ++rt)
#pragma unroll
      for (int r = 0; r < 4; ++r) z[rt * 4 + r] += EXP2(av[rt][r]);
  }
#pragma unroll
  for (int off = 1; off < 16; off <<= 1) {
#pragma unroll
    for (int i = 0; i < 16; ++i) z[i] += __shfl_xor(z[i], off);
  }
  if (l == 0) {
#pragma unroll
    for (int rt = 0; rt < 4; ++rt)
#pragma unroll
      for (int r = 0; r < 4; ++r)
        atomicAdd(&zrow[rt * 16 + quad * 4 + r], z[rt * 4 + r]);
  }
  __syncthreads();  // zrow complete
  if (tid < 64) lse[bh * 1024 + r0 + tid] = __log2f(zrow[tid]);
  float nlb[16];  // -log2(Z)
#pragma unroll
  for (int rt = 0; rt < 4; ++rt)
#pragma unroll
    for (int r = 0; r < 4; ++r)
      nlb[rt * 4 + r] = -__log2f(zrow[rt * 16 + quad * 4 + r]);

  // ---- pass 2: column sums of p and p*log2p ----
  // d = score + (-log2 Z); p = exp2(d); cs += p; cp += p*d. 4 VALU/element.
  for (int s = 0; s < 8; ++s) {
    const bf16x8 c0 = kf0, c1 = kf1;
    if (s < 7) {
      kf0 = *(const bf16x8*)(kfrag + (size_t)(s + 1) * 8192);
      kf1 = *(const bf16x8*)(kfrag + (size_t)(s + 1) * 8192 + 32);
    }
    f32x4 av[4];
#pragma unroll
    for (int rt = 0; rt < 4; ++rt) {
      av[rt] = MFMA16(aq0[rt], c0, zero);
      av[rt] = MFMA16(aq1[rt], c1, av[rt]);
    }
    float cs = 0.f, cp = 0.f;
#pragma unroll
    for (int rt = 0; rt < 4; ++rt) {
#pragma unroll
      for (int r = 0; r < 4; ++r) {
        const float d = av[rt][r] + nlb[rt * 4 + r];
        const float t = EXP2(d);
        cs += t;
        cp = fmaf(t, d, cp);
      }
    }
    cs += __shfl_xor(cs, 16); cs += __shfl_xor(cs, 32);
    cp += __shfl_xor(cp, 16); cp += __shfl_xor(cp, 32);
    if (lane < 16) {  // wave-private columns: plain LDS accumulate
      sS[s * 128 + w * 16 + l] += cs;
      sP[s * 128 + w * 16 + l] += cp;
    }
  }
  __syncthreads();
  for (int i = tid; i < 1024; i += 512) {
    atomicAdd(&colSP[i], sS[i]);
    atomicAdd(&colSP[1024 + i], sP[i]);
  }
}

// --- 5. masked AV -> ctxb. Mask recomputed locally; early-out first. -------
__global__ __launch_bounds__(256) void k_av(
    const __bf16* __restrict__ qb, const __bf16* __restrict__ kb,
    const __bf16* __restrict__ v, const float* __restrict__ lse,
    const float* __restrict__ colSP, const int* __restrict__ cur_epoch,
    __bf16* __restrict__ ctxb)
{
  const int tid = threadIdx.x;
  const int bh = blockIdx.x, r0 = blockIdx.y * 32;
  const int b_ = bh / 12, h = bh % 12;
  __shared__ float qs[32][64];
  __shared__ float pbuf[4][8][64];
  __shared__ float maskS[1024];
  __shared__ int anyKeep;
  if (tid == 0) anyKeep = 0;
  __syncthreads();
  // mask prologue: thr from cur_epoch; entropy per column from colSP (L2-hot)
  {
    const int ce = cur_epoch[0];
    float factor = 0.f;
    for (int i = 1; i <= ce; ++i) factor += __expf(-(float)i);
    factor *= 5.0f;
    const float thr = __logf(768.0f) - factor;
    for (int j = tid; j < 1024; j += 256) {
      const float s = colSP[j];
      const float ent = __logf(s) - (colSP[1024 + j] * LN2) / s;
      const int keep = (ent <= thr) ? 1 : 0;
      maskS[j] = keep ? 1.0f : 0.0f;
      if (keep) anyKeep = 1;  // benign race: all writers store 1
    }
  }
  __syncthreads();
  if (anyKeep == 0) return;  // uniform; ctxb unused downstream in this case
  for (int i = tid; i < 2048; i += 256)
    qs[i >> 6][i & 63] = (float)qb[((size_t)bh * 1024 + r0) * 64 + i];
  __syncthreads();
  const int w = tid >> 6, l = tid & 63, rb = w * 8;
  float ls[8];
#pragma unroll
  for (int i = 0; i < 8; ++i) ls[i] = lse[bh * 1024 + r0 + rb + i];
  float acc[8] = {};
  for (int chunk = 0; chunk < 16; ++chunk) {
    const float mk = maskS[chunk * 64 + l];
    if (__ballot(mk != 0.0f) == 0ull) continue;  // block-uniform
    const __bf16* kp = kb + ((size_t)bh * 1024 + chunk * 64 + l) * 64;
    float s[8] = {};
    for (int d0 = 0; d0 < 64; d0 += 8) {
      const bf16x8 kf = *(const bf16x8*)(kp + d0);
#pragma unroll
      for (int dd = 0; dd < 8; ++dd) {
        const float kv = (float)kf[dd];
#pragma unroll
        for (int i = 0; i < 8; ++i) s[i] += qs[rb + i][d0 + dd] * kv;
      }
    }
    __syncthreads();
#pragma unroll
    for (int i = 0; i < 8; ++i)
      pbuf[w][i][l] = EXP2(s[i] - ls[i]) * mk;
    __syncthreads();
    const __bf16* vp = v + ((size_t)bh * 1024 + chunk * 64) * 64 + l;
    for (int jj = 0; jj < 64; ++jj) {
      const float vv = (float)vp[(size_t)jj * 64];
#pragma unroll
      for (int i = 0; i < 8; ++i) acc[i] += pbuf[w][i][jj] * vv;
    }
  }
#pragma unroll
  for (int i = 0; i < 8; ++i)
    ctxb[((size_t)(b_ * 1024 + r0 + rb + i)) * 768 + h * 64 + l] = (__bf16)acc[i];
}

// --- 6. proj GEMM: out = ctxb @ pwb.T + bias; keep-any recomputed. ---------
__global__ __launch_bounds__(256) void kg_proj(
    const __bf16* __restrict__ A, const __bf16* __restrict__ Bm,
    const float* __restrict__ bias, const float* __restrict__ colSP,
    const int* __restrict__ cur_epoch, float* __restrict__ out)
{
  const int tid = threadIdx.x;
  const int w = tid >> 6, lane = tid & 63, quad = lane >> 4, l = lane & 15;
  const int r0 = blockIdx.y * 64, c0 = blockIdx.x * 64;
  __shared__ int anyKeep;
  if (tid == 0) anyKeep = 0;
  __syncthreads();
  {
    const int ce = cur_epoch[0];
    float factor = 0.f;
    for (int i = 1; i <= ce; ++i) factor += __expf(-(float)i);
    factor *= 5.0f;
    const float thr = __logf(768.0f) - factor;
    for (int j = tid; j < 1024; j += 256) {
      const float s = colSP[j];
      const float ent = __logf(s) - (colSP[1024 + j] * LN2) / s;
      if (ent <= thr) anyKeep = 1;  // benign race
    }
  }
  __syncthreads();
  if (anyKeep == 0) {  // ctx == 0 -> out = bias (uniform branch)
#pragma unroll
    for (int ct = 0; ct < 4; ++ct) {
      const int c = c0 + ct * 16 + l;
      const float bv = bias[c];
#pragma unroll
      for (int i = 0; i < 4; ++i) {
        const int rg = r0 + w * 16 + quad * 4 + i;
        out[(size_t)rg * 768 + c] = bv;
      }
    }
    return;
  }
  __shared__ __bf16 As[64 * 72];
  __shared__ __bf16 Bs[64 * 72];
  const int row = tid >> 3, ko = (tid & 7) * 8;
  const f32x4 zero = {0.f, 0.f, 0.f, 0.f};
  f32x4 acc[4];
#pragma unroll
  for (int ct = 0; ct < 4; ++ct) acc[ct] = zero;

  uint4 a0 = *(const uint4*)(A + (size_t)(r0 + row) * 768 + ko);
  uint4 a1 = *(const uint4*)(A + (size_t)(r0 + row + 32) * 768 + ko);
  uint4 b0 = *(const uint4*)(Bm + (size_t)(c0 + row) * 768 + ko);
  uint4 b1 = *(const uint4*)(Bm + (size_t)(c0 + row + 32) * 768 + ko);

  for (int k0 = 0; k0 < 768; k0 += 64) {
    __syncthreads();
    *(uint4*)&As[row * 72 + ko] = a0;
    *(uint4*)&As[(row + 32) * 72 + ko] = a1;
    *(uint4*)&Bs[row * 72 + ko] = b0;
    *(uint4*)&Bs[(row + 32) * 72 + ko] = b1;
    __syncthreads();
    if (k0 < 704) {
      a0 = *(const uint4*)(A + (size_t)(r0 + row) * 768 + k0 + 64 + ko);
      a1 = *(const uint4*)(A + (size_t)(r0 + row + 32) * 768 + k0 + 64 + ko);
      b0 = *(const uint4*)(Bm + (size_t)(c0 + row) * 768 + k0 + 64 + ko);
      b1 = *(const uint4*)(Bm + (size_t)(c0 + row + 32) * 768 + k0 + 64 + ko);
    }
    const bf16x8 af0 = *(const bf16x8*)&As[(w * 16 + l) * 72 + quad * 8];
    const bf16x8 af1 = *(const bf16x8*)&As[(w * 16 + l) * 72 + 32 + quad * 8];
#pragma unroll
    for (int ct = 0; ct < 4; ++ct) {
      const bf16x8 bf0 = *(const bf16x8*)&Bs[(ct * 16 + l) * 72 + quad * 8];
      const bf16x8 bf1 = *(const bf16x8*)&Bs[(ct * 16 + l) * 72 + 32 + quad * 8];
      acc[ct] = MFMA16(af0, bf0, acc[ct]);
      acc[ct] = MFMA16(af1, bf1, acc[ct]);
    }
  }
#pragma unroll
  for (int ct = 0; ct < 4; ++ct) {
    const int c = c0 + ct * 16 + l;
#pragma unroll
    for (int i = 0; i < 4; ++i) {
      const int rg = r0 + w * 16 + quad * 4 + i;
      out[(size_t)rg * 768 + c] = acc[ct][i] + bias[c];
    }
  }
}

extern "C" void kernel_launch(void* const* d_in, const int* in_sizes, int n_in,
                              void* d_out, int out_size, void* d_ws, size_t ws_size,
                              hipStream_t stream)
{
  const float* x      = (const float*)d_in[0];
  const float* qkv_w  = (const float*)d_in[1];
  const float* proj_w = (const float*)d_in[2];
  const float* proj_b = (const float*)d_in[3];
  const int*   cur_ep = (const int*)d_in[4];

  char* W = (char*)d_ws;
  __bf16* xb    = (__bf16*)(W + 0);
  __bf16* qwb   = (__bf16*)(W + 6291456);
  __bf16* pwb   = (__bf16*)(W + 9830400);
  __bf16* qb    = (__bf16*)(W + 11010048);
  __bf16* kb    = (__bf16*)(W + 17301504);
  __bf16* v     = (__bf16*)(W + 23592960);
  __bf16* ctxb  = (__bf16*)(W + 36175872);
  float*  lse   = (float*) (W + 42467328);
  float*  colSP = (float*) (W + 42668544);
  float*  out   = (float*)d_out;

  kc_conv<<<5376, 256, 0, stream>>>(x, qkv_w, proj_w, xb, qwb, pwb, colSP);
  kg_qkv<<<dim3(36, 32), 256, 0, stream>>>(xb, qwb, qb, kb, v);
  ks_fused<<<dim3(48, 16), 512, 0, stream>>>(qb, kb, lse, colSP);
  k_av<<<dim3(48, 32), 256, 0, stream>>>(qb, kb, v, lse, colSP, cur_ep, ctxb);
  kg_proj<<<dim3(12, 64), 256, 0, stream>>>(ctxb, pwb, proj_b, colSP, cur_ep, out);
}